// Round 4
// baseline (121.786 us; speedup 1.0000x reference)
//
#include <hip/hip_runtime.h>
#include <hip/hip_cooperative_groups.h>
#include <cstddef>
#include <math.h>

namespace cg = cooperative_groups;

#define BD 8
#define TD 256
#define SD 256
#define HD 512
#define K2F 2.885390081777927f    // 2*log2(e): arg of exp2 for e^(2x)

#define EXP2(x) __builtin_amdgcn_exp2f(x)
#define RCP(x)  __builtin_amdgcn_rcpf(x)

typedef __attribute__((ext_vector_type(8))) _Float16 half8;
typedef __attribute__((ext_vector_type(4))) _Float16 half4;
typedef __attribute__((ext_vector_type(4))) float float4v;

// exp2 with arg clamped so E in [2^-80, 2^80]: products overflow to inf -> rcp -> 0,
// underflow to 0 -> r = 1; no inf*0 NaN path possible.
__device__ __forceinline__ float exp2_sat(float x) {
    return EXP2(fminf(fmaxf(x, -80.0f), 80.0f));
}

#define LSTR 40   // LDS row stride (halves) for proj staging

// ================= PHASE A, 512-thread variant (proven r2 code) =================
__device__ __forceinline__ void phaseA(
    int bid, int tid, float* smem,
    const float* __restrict__ enc, const float* __restrict__ qry,
    const float* __restrict__ Wh,  const float* __restrict__ Ws,
    float* __restrict__ encT, float* __restrict__ qryf)
{
    const int l  = tid & 63;
    const int w  = tid >> 6;
    const int rf = l & 15;
    const int q  = l >> 4;

    _Float16* LA = (_Float16*)smem;            // 64*40 halves = 5120 B
    _Float16* LB = (_Float16*)(smem + 1280);   // +5120 B

    const int x  = bid & 7;                    // XCD / owning batch
    const int k  = bid >> 3;                   // 0..63
    const bool isq = k >= 32;
    const int kk = k & 31;                     // 0..31
    const int my = (isq ? 32 : 0) + x * 4 + (kk & 3);
    const int n0 = (kk >> 2) * 64;
    const int m0 = my * 64;                    // stacked row 0..4095

    const int srow = tid >> 3;                 // staging row 0..63
    const int scol = (tid & 7) * 4;            // staging col (floats)
    const float* Abase = isq
        ? qry + (size_t)(m0 - 2048 + srow) * HD + scol
        : enc + (size_t)(m0 + srow) * HD + scol;
    const float* Bbase = (isq ? Ws : Wh) + (size_t)(n0 + srow) * HD + scol;

    const int mi = (w & 3) * 16;               // wave row-strip
    const int ni = (w >> 2) * 32;              // wave col-strip (2 MFMA tiles)

    float4v acc[2] = {{0,0,0,0},{0,0,0,0}};

    float4 a0 = *(const float4*)(Abase);
    float4 b0 = *(const float4*)(Bbase);

    for (int ks = 0; ks < 16; ++ks) {
        if (ks) __syncthreads();
        {
            half4 ha, hb;
            ha[0]=(_Float16)a0.x; ha[1]=(_Float16)a0.y; ha[2]=(_Float16)a0.z; ha[3]=(_Float16)a0.w;
            hb[0]=(_Float16)b0.x; hb[1]=(_Float16)b0.y; hb[2]=(_Float16)b0.z; hb[3]=(_Float16)b0.w;
            *(half4*)&LA[srow * LSTR + scol] = ha;
            *(half4*)&LB[srow * LSTR + scol] = hb;
        }
        __syncthreads();
        if (ks + 1 < 16) {
            const int ko = (ks + 1) * 32;
            a0 = *(const float4*)(Abase + ko);
            b0 = *(const float4*)(Bbase + ko);
        }
        half8 ah = *(const half8*)&LA[(mi + rf) * LSTR + q * 8];
        #pragma unroll
        for (int j = 0; j < 2; ++j) {
            half8 bh = *(const half8*)&LB[(ni + j * 16 + rf) * LSTR + q * 8];
            acc[j] = __builtin_amdgcn_mfma_f32_16x16x32_f16(ah, bh, acc[j], 0, 0, 0);
        }
    }

    // Epilogue (verified map: m-local = mi + q*4 + r, n-local = ni + j*16 + rf).
    if (!isq) {
        const int b  = m0 >> 8;                // == x by construction
        const int sb = (m0 & 255) + mi + q * 4;
        float* base = encT + (size_t)b * HD * SD;
        #pragma unroll
        for (int j = 0; j < 2; ++j) {
            float4 o = make_float4(exp2_sat(acc[j][0]*K2F), exp2_sat(acc[j][1]*K2F),
                                   exp2_sat(acc[j][2]*K2F), exp2_sat(acc[j][3]*K2F));
            *(float4*)(base + (size_t)(n0 + ni + j * 16 + rf) * SD + sb) = o;
        }
    } else {
        const int mrow = (m0 - 2048) + mi + q * 4;
        #pragma unroll
        for (int j = 0; j < 2; ++j)
            #pragma unroll
            for (int r = 0; r < 4; ++r)
                qryf[(size_t)(mrow + r) * HD + n0 + ni + j * 16 + rf] =
                    exp2_sat(acc[j][r] * K2F);
    }
}

// ================= PHASE A, 1024-thread variant (same tile, 16 waves, 1 MFMA/wave) ========
// Same 64x64 tile per block id (identical bid->tile map as phaseA: x=bid&7, k=bid>>3),
// same LSTR LDS layout, same verified epilogue map (j fixed to 0, ni granularity 16).
// Staging: threads 0-511 stage the A tile, 512-1023 stage the B tile (1 float4 each).
__device__ __forceinline__ void phaseA1024(
    int bid, int tid, float* smem,
    const float* __restrict__ enc, const float* __restrict__ qry,
    const float* __restrict__ Wh,  const float* __restrict__ Ws,
    float* __restrict__ encT, float* __restrict__ qryf)
{
    const int l  = tid & 63;
    const int w  = tid >> 6;                   // wave 0..15
    const int rf = l & 15;
    const int q  = l >> 4;

    _Float16* LA = (_Float16*)smem;            // 64*40 halves = 5120 B
    _Float16* LB = (_Float16*)(smem + 1280);   // +5120 B

    const int x  = bid & 7;                    // XCD / owning batch
    const int k  = bid >> 3;                   // 0..63
    const bool isq = k >= 32;
    const int kk = k & 31;                     // 0..31
    const int my = (isq ? 32 : 0) + x * 4 + (kk & 3);
    const int n0 = (kk >> 2) * 64;
    const int m0 = my * 64;                    // stacked row 0..4095

    const bool stagesA = (tid < 512);          // wave-uniform (waves 0-7 vs 8-15)
    const int srow = (tid >> 3) & 63;          // staging row 0..63
    const int scol = (tid & 7) * 4;            // staging col (floats)
    const float* Sbase = stagesA
        ? (isq ? qry + (size_t)(m0 - 2048 + srow) * HD
               : enc + (size_t)(m0 + srow) * HD) + scol
        : (isq ? Ws : Wh) + (size_t)(n0 + srow) * HD + scol;
    _Float16* Ldst = (stagesA ? LA : LB) + srow * LSTR + scol;

    const int mi = (w & 3) * 16;               // wave row-strip (4)
    const int ni = (w >> 2) * 16;              // wave col-strip (4)

    float4v acc = {0, 0, 0, 0};

    float4 a0 = *(const float4*)(Sbase);

    for (int ks = 0; ks < 16; ++ks) {
        if (ks) __syncthreads();
        {
            half4 ha;
            ha[0]=(_Float16)a0.x; ha[1]=(_Float16)a0.y; ha[2]=(_Float16)a0.z; ha[3]=(_Float16)a0.w;
            *(half4*)Ldst = ha;
        }
        __syncthreads();
        if (ks + 1 < 16) a0 = *(const float4*)(Sbase + (ks + 1) * 32);
        half8 ah = *(const half8*)&LA[(mi + rf) * LSTR + q * 8];
        half8 bh = *(const half8*)&LB[(ni + rf) * LSTR + q * 8];
        acc = __builtin_amdgcn_mfma_f32_16x16x32_f16(ah, bh, acc, 0, 0, 0);
    }

    // Epilogue (verified map: m-local = mi + q*4 + r, n-local = ni + rf).
    if (!isq) {
        const int b  = m0 >> 8;
        const int sb = (m0 & 255) + mi + q * 4;
        float* base = encT + (size_t)b * HD * SD;
        float4 o = make_float4(exp2_sat(acc[0]*K2F), exp2_sat(acc[1]*K2F),
                               exp2_sat(acc[2]*K2F), exp2_sat(acc[3]*K2F));
        *(float4*)(base + (size_t)(n0 + ni + rf) * SD + sb) = o;
    } else {
        const int mrow = (m0 - 2048) + mi + q * 4;
        #pragma unroll
        for (int r = 0; r < 4; ++r)
            qryf[(size_t)(mrow + r) * HD + n0 + ni + rf] = exp2_sat(acc[r] * K2F);
    }
}

// ================= PHASE B (device fn, templated on t-rows per block) =================
// smem layout: qls[512*TT] | pls[1024*TT] | wls[256*TT]  (floats). TT=4 -> 28 KB, TT=2 -> 14 KB.
// Summation order identical for both TT -> bitwise-identical output.
template<int TT>
__device__ __forceinline__ void phaseB(
    int b, int t0, int tid, float* smem,
    const float* __restrict__ enc, const float* __restrict__ encT,
    const float* __restrict__ qryf, const float* __restrict__ v,
    const int* __restrict__ lens, float* __restrict__ out)
{
    const int l = tid & 63;
    const int w = tid >> 6;

    float* qls = smem;               // [j][t] 512*TT floats
    float* pls = smem + 512 * TT;    // [slice(4)][t(TT)][s(256)]; aliased avred
    float* wls = smem + 1536 * TT;   // [t][s] 256*TT floats

    {   // stage E_q transposed: qls[j*TT + t]
        const float* qf = qryf + ((size_t)b * TD + t0) * HD;
        #pragma unroll
        for (int t = 0; t < TT; ++t) qls[tid * TT + t] = qf[t * HD + tid];
    }
    __syncthreads();

    // ---- scores: wave w covers j-slice w; lane owns s = 4l..4l+3 ----
    float a[TT][4];
    #pragma unroll
    for (int t = 0; t < TT; ++t)
        #pragma unroll
        for (int c = 0; c < 4; ++c) a[t][c] = 0.0f;
    {
        const float* ep = encT + (size_t)b * HD * SD + (size_t)(w * 64) * SD + l * 4;
        const int jbase = w * 64;
        #pragma unroll 4
        for (int jj = 0; jj < 64; ++jj) {
            float4 e = *(const float4*)(ep + (size_t)jj * SD);  // E_e, coalesced
            float vj = v[jbase + jj];                           // uniform per wave
            float qv[TT];
            #pragma unroll
            for (int t = 0; t < TT; ++t) qv[t] = qls[(jbase + jj) * TT + t];
            float ev[4] = {e.x, e.y, e.z, e.w};
            #pragma unroll
            for (int t = 0; t < TT; ++t)
                #pragma unroll
                for (int c = 0; c < 4; ++c) {
                    float p = fmaf(ev[c], qv[t], 1.0f);
                    a[t][c] = fmaf(vj, RCP(p), a[t][c]);
                }
        }
    }
    // two-stage partial accumulate
    if (w < 4) {
        #pragma unroll
        for (int t = 0; t < TT; ++t)
            *(float4*)&pls[(w * TT + t) * 256 + l * 4] =
                make_float4(a[t][0], a[t][1], a[t][2], a[t][3]);
    }
    __syncthreads();
    if (w >= 4) {
        #pragma unroll
        for (int t = 0; t < TT; ++t) {
            float4 c4 = *(const float4*)&pls[((w - 4) * TT + t) * 256 + l * 4];
            c4.x += a[t][0]; c4.y += a[t][1]; c4.z += a[t][2]; c4.w += a[t][3];
            *(float4*)&pls[((w - 4) * TT + t) * 256 + l * 4] = c4;
        }
    }
    __syncthreads();

    // ---- combine 4 slices + masked softmax: wave t<TT handles t; lane owns 4 s ----
    if (w < TT) {
        const int t = w;
        float p[4] = {0, 0, 0, 0};
        #pragma unroll
        for (int g = 0; g < 4; ++g) {
            float4 pp = *(const float4*)&pls[(g * TT + t) * 256 + l * 4];
            p[0] += pp.x; p[1] += pp.y; p[2] += pp.z; p[3] += pp.w;
        }
        const int len = lens[b];
        const int s0 = l * 4;
        float sc[4];
        #pragma unroll
        for (int c = 0; c < 4; ++c)
            sc[c] = (s0 + c < len) ? -2.0f * p[c] : -INFINITY;
        float mx = fmaxf(fmaxf(sc[0], sc[1]), fmaxf(sc[2], sc[3]));
        #pragma unroll
        for (int off = 32; off; off >>= 1) mx = fmaxf(mx, __shfl_xor(mx, off));
        float ex[4]; float sum = 0.0f;
        #pragma unroll
        for (int c = 0; c < 4; ++c) { ex[c] = __expf(sc[c] - mx); sum += ex[c]; }
        #pragma unroll
        for (int off = 32; off; off >>= 1) sum += __shfl_xor(sum, off);
        const float inv = RCP(sum);
        *(float4*)&wls[t * SD + s0] = make_float4(ex[0]*inv, ex[1]*inv, ex[2]*inv, ex[3]*inv);
    }
    __syncthreads();

    // ---- AV: thread owns (h-float4, s-slice sg of 64); accumulates all TT t ----
    const int sg = tid >> 7;          // 0..3 (wave-uniform)
    const int h4 = (tid & 127) * 4;
    float* avred = pls;               // [slice(2)][t(TT)][h(512)] = 1024*TT floats
    float4 o[TT];
    #pragma unroll
    for (int t = 0; t < TT; ++t) o[t] = make_float4(0.f, 0.f, 0.f, 0.f);
    {
        const float* eb = enc + (size_t)b * SD * HD + h4;
        #pragma unroll 2
        for (int ss = 0; ss < 64; ++ss) {
            const int s = sg * 64 + ss;
            float4 evv = *(const float4*)(eb + (size_t)s * HD);
            float wt[TT];
            #pragma unroll
            for (int t = 0; t < TT; ++t) wt[t] = wls[t * SD + s];
            #pragma unroll
            for (int t = 0; t < TT; ++t) {
                o[t].x = fmaf(wt[t], evv.x, o[t].x);
                o[t].y = fmaf(wt[t], evv.y, o[t].y);
                o[t].z = fmaf(wt[t], evv.z, o[t].z);
                o[t].w = fmaf(wt[t], evv.w, o[t].w);
            }
        }
    }
    if (sg < 2) {
        #pragma unroll
        for (int t = 0; t < TT; ++t)
            *(float4*)&avred[(size_t)(sg * TT + t) * 512 + h4] = o[t];
    }
    __syncthreads();
    if (sg >= 2) {
        #pragma unroll
        for (int t = 0; t < TT; ++t) {
            float4 c4 = *(const float4*)&avred[(size_t)((sg - 2) * TT + t) * 512 + h4];
            c4.x += o[t].x; c4.y += o[t].y; c4.z += o[t].z; c4.w += o[t].w;
            *(float4*)&avred[(size_t)((sg - 2) * TT + t) * 512 + h4] = c4;
        }
    }
    __syncthreads();

    // final reduce + store: thread owns (t = tid>>7, h-float4); TT*128 threads active
    if (tid < TT * 128) {
        const int t  = tid >> 7;
        const int hh = (tid & 127) * 4;
        float4 x0 = *(const float4*)&avred[(size_t)(0 * TT + t) * 512 + hh];
        float4 x1 = *(const float4*)&avred[(size_t)(1 * TT + t) * 512 + hh];
        float4 r = make_float4(x0.x + x1.x, x0.y + x1.y, x0.z + x1.z, x0.w + x1.w);
        *(float4*)(out + ((size_t)b * TD + t0 + t) * HD + hh) = r;
    }
}

// ============ fusedT: grid 512 (PROVEN coop grid) x 1024 threads = 8 waves/SIMD ============
// __launch_bounds__(1024, 8): 8 waves/EU minimum -> compiler forced to <=64 VGPR.
// Phase A: 16-wave variant, same tile map. Phase B: two independent 512-thread subs,
// each running the proven phaseB<2> in its own 14 KB LDS half; barrier sequences of the
// two subs are identical so block-wide __syncthreads stays aligned.
__global__ __launch_bounds__(1024, 8) void fusedT(
    const float* __restrict__ enc, const float* __restrict__ qry,
    const float* __restrict__ Wh,  const float* __restrict__ Ws,
    const float* __restrict__ v,   const int* __restrict__ lens,
    float* __restrict__ encT, float* __restrict__ qryf, float* __restrict__ out)
{
    __shared__ float smem[7168];   // 28 KB: phaseA uses 10 KB; phaseB 2 x 14 KB
    const int bid = blockIdx.x;
    const int tid = threadIdx.x;

    phaseA1024(bid, tid, smem, enc, qry, Wh, Ws, encT, qryf);

    cg::this_grid().sync();

    const int sub  = tid >> 9;        // 0 or 1 (wave-uniform)
    const int stid = tid & 511;
    phaseB<2>(bid & 7, (bid >> 3) * 4 + sub * 2, stid, smem + sub * 3584,
              enc, encT, qryf, v, lens, out);
}

// ============ fused512: proven r2 config (~102 us), 28 KB LDS ============
__global__ __launch_bounds__(512) void fused512(
    const float* __restrict__ enc, const float* __restrict__ qry,
    const float* __restrict__ Wh,  const float* __restrict__ Ws,
    const float* __restrict__ v,   const int* __restrict__ lens,
    float* __restrict__ encT, float* __restrict__ qryf, float* __restrict__ out)
{
    __shared__ float smem[7168];   // 28 KB
    const int bid = blockIdx.x;
    phaseA(bid, threadIdx.x, smem, enc, qry, Wh, Ws, encT, qryf);
    cg::this_grid().sync();
    phaseB<4>(bid & 7, (bid >> 3) * 4, threadIdx.x, smem,
              enc, encT, qryf, v, lens, out);
}

// ================= fallback pair (proven R8 proj + R7 attn) =================
__global__ __launch_bounds__(256) void proj_fb(
    const float* __restrict__ enc, const float* __restrict__ qry,
    const float* __restrict__ Wh,  const float* __restrict__ Ws,
    float* __restrict__ encT, float* __restrict__ qryf)
{
    __shared__ _Float16 LA[64 * LSTR], LB[64 * LSTR];

    const int tid = threadIdx.x;
    const int l = tid & 63, w = tid >> 6;
    const int rf = l & 15, q = l >> 4;
    const int my = blockIdx.y;
    const bool isq = my >= 32;
    const int m0 = my * 64;
    const int n0 = blockIdx.x * 64;

    const int srow = tid >> 2;
    const int scol = (tid & 3) * 8;
    const float* Abase = isq
        ? qry + (size_t)(m0 - 2048 + srow) * HD + scol
        : enc + (size_t)(m0 + srow) * HD + scol;
    const float* Bbase = (isq ? Ws : Wh) + (size_t)(n0 + srow) * HD + scol;

    const int mi = (w & 1) * 32, ni = (w >> 1) * 32;
    float4v acc[2][2] = {{{0,0,0,0},{0,0,0,0}},{{0,0,0,0},{0,0,0,0}}};

    float4 a0 = *(const float4*)(Abase);
    float4 a1 = *(const float4*)(Abase + 4);
    float4 b0 = *(const float4*)(Bbase);
    float4 b1 = *(const float4*)(Bbase + 4);

    for (int ks = 0; ks < 16; ++ks) {
        if (ks) __syncthreads();
        {
            float af[8] = {a0.x,a0.y,a0.z,a0.w,a1.x,a1.y,a1.z,a1.w};
            float bf[8] = {b0.x,b0.y,b0.z,b0.w,b1.x,b1.y,b1.z,b1.w};
            half8 ha, hb;
            #pragma unroll
            for (int i = 0; i < 8; ++i) { ha[i] = (_Float16)af[i]; hb[i] = (_Float16)bf[i]; }
            *(half8*)&LA[srow * LSTR + scol] = ha;
            *(half8*)&LB[srow * LSTR + scol] = hb;
        }
        __syncthreads();
        if (ks + 1 < 16) {
            const int ko = (ks + 1) * 32;
            a0 = *(const float4*)(Abase + ko);
            a1 = *(const float4*)(Abase + ko + 4);
            b0 = *(const float4*)(Bbase + ko);
            b1 = *(const float4*)(Bbase + ko + 4);
        }
        half8 ah[2], bh[2];
        #pragma unroll
        for (int i = 0; i < 2; ++i) {
            ah[i] = *(const half8*)&LA[(mi + i * 16 + rf) * LSTR + q * 8];
            bh[i] = *(const half8*)&LB[(ni + i * 16 + rf) * LSTR + q * 8];
        }
        #pragma unroll
        for (int i = 0; i < 2; ++i)
            #pragma unroll
            for (int j = 0; j < 2; ++j)
                acc[i][j] = __builtin_amdgcn_mfma_f32_16x16x32_f16(ah[i], bh[j], acc[i][j], 0, 0, 0);
    }

    if (!isq) {
        const int b  = m0 >> 8;
        const int sb = (m0 & 255) + mi + q * 4;
        float* base = encT + (size_t)b * HD * SD;
        #pragma unroll
        for (int i = 0; i < 2; ++i)
            #pragma unroll
            for (int j = 0; j < 2; ++j) {
                float4 o = make_float4(exp2_sat(acc[i][j][0]*K2F), exp2_sat(acc[i][j][1]*K2F),
                                       exp2_sat(acc[i][j][2]*K2F), exp2_sat(acc[i][j][3]*K2F));
                *(float4*)(base + (size_t)(n0 + ni + j * 16 + rf) * SD + sb + i * 16) = o;
            }
    } else {
        const int mrow = (m0 - 2048) + mi + q * 4;
        #pragma unroll
        for (int i = 0; i < 2; ++i)
            #pragma unroll
            for (int j = 0; j < 2; ++j)
                #pragma unroll
                for (int r = 0; r < 4; ++r)
                    qryf[(size_t)(mrow + i * 16 + r) * HD + n0 + ni + j * 16 + rf] =
                        exp2_sat(acc[i][j][r] * K2F);
    }
}

__global__ __launch_bounds__(512) void attn_fb(
    const float* __restrict__ enc, const float* __restrict__ encT,
    const float* __restrict__ qryf, const float* __restrict__ v,
    const int* __restrict__ lens, float* __restrict__ out)
{
    __shared__ float qls[HD * 4];
    __shared__ float pls[8 * 4 * 256];
    __shared__ float wls[4 * SD];

    const int blk = blockIdx.x;
    const int b   = blk >> 6;
    const int t0  = (blk & 63) * 4;
    const int tid = threadIdx.x;
    const int w   = tid >> 6;
    const int l   = tid & 63;

    {
        const float* qf = qryf + ((size_t)b * TD + t0) * HD;
        float4 qv;
        qv.x = qf[0 * HD + tid]; qv.y = qf[1 * HD + tid];
        qv.z = qf[2 * HD + tid]; qv.w = qf[3 * HD + tid];
        *(float4*)&qls[tid * 4] = qv;
    }
    __syncthreads();

    float a[4][4];
    #pragma unroll
    for (int t = 0; t < 4; ++t)
        #pragma unroll
        for (int c = 0; c < 4; ++c) a[t][c] = 0.0f;
    {
        const float* ep = encT + (size_t)b * HD * SD + (size_t)(w * 64) * SD + l * 4;
        const int jbase = w * 64;
        #pragma unroll 4
        for (int jj = 0; jj < 64; ++jj) {
            float4 e = *(const float4*)(ep + (size_t)jj * SD);
            float4 q4 = *(const float4*)&qls[(jbase + jj) * 4];
            float vj = v[jbase + jj];
            float ev[4] = {e.x, e.y, e.z, e.w};
            float qv[4] = {q4.x, q4.y, q4.z, q4.w};
            #pragma unroll
            for (int t = 0; t < 4; ++t)
                #pragma unroll
                for (int c = 0; c < 4; ++c) {
                    float p = fmaf(ev[c], qv[t], 1.0f);
                    a[t][c] = fmaf(vj, RCP(p), a[t][c]);
                }
        }
    }
    #pragma unroll
    for (int t = 0; t < 4; ++t)
        *(float4*)&pls[(w * 4 + t) * 256 + l * 4] = make_float4(a[t][0], a[t][1], a[t][2], a[t][3]);
    __syncthreads();

    if (w < 4) {
        const int t = w;
        float p[4] = {0, 0, 0, 0};
        #pragma unroll
        for (int g = 0; g < 8; ++g) {
            float4 pp = *(const float4*)&pls[(g * 4 + t) * 256 + l * 4];
            p[0] += pp.x; p[1] += pp.y; p[2] += pp.z; p[3] += pp.w;
        }
        const int len = lens[b];
        const int s0 = l * 4;
        float sc[4];
        #pragma unroll
        for (int c = 0; c < 4; ++c)
            sc[c] = (s0 + c < len) ? -2.0f * p[c] : -INFINITY;
        float mx = fmaxf(fmaxf(sc[0], sc[1]), fmaxf(sc[2], sc[3]));
        #pragma unroll
        for (int off = 32; off; off >>= 1) mx = fmaxf(mx, __shfl_xor(mx, off));
        float ex[4]; float sum = 0.0f;
        #pragma unroll
        for (int c = 0; c < 4; ++c) { ex[c] = __expf(sc[c] - mx); sum += ex[c]; }
        #pragma unroll
        for (int off = 32; off; off >>= 1) sum += __shfl_xor(sum, off);
        const float inv = RCP(sum);
        *(float4*)&wls[t * SD + s0] = make_float4(ex[0]*inv, ex[1]*inv, ex[2]*inv, ex[3]*inv);
    }
    __syncthreads();

    const int g  = tid >> 7;
    const int h4 = (tid & 127) * 4;
    float* avred = pls;
    {
        const float* eb = enc + (size_t)b * SD * HD + h4;
        float4 o[4] = {{0,0,0,0},{0,0,0,0},{0,0,0,0},{0,0,0,0}};
        #pragma unroll 2
        for (int ss = 0; ss < 64; ++ss) {
            const int s = g * 64 + ss;
            float4 evv = *(const float4*)(eb + (size_t)s * HD);
            float wt[4];
            #pragma unroll
            for (int t = 0; t < 4; ++t) wt[t] = wls[t * SD + s];
            #pragma unroll
            for (int t = 0; t < 4; ++t) {
                o[t].x = fmaf(wt[t], evv.x, o[t].x);
                o[t].y = fmaf(wt[t], evv.y, o[t].y);
                o[t].z = fmaf(wt[t], evv.z, o[t].z);
                o[t].w = fmaf(wt[t], evv.w, o[t].w);
            }
        }
        #pragma unroll
        for (int t = 0; t < 4; ++t)
            *(float4*)&avred[(size_t)(g * 4 + t) * 512 + h4] = o[t];
    }
    __syncthreads();
    {
        const int t  = tid >> 7;
        const int hh = (tid & 127) * 4;
        float4 r = {0, 0, 0, 0};
        #pragma unroll
        for (int gg = 0; gg < 4; ++gg) {
            float4 x = *(const float4*)&avred[(size_t)(gg * 4 + t) * 512 + hh];
            r.x += x.x; r.y += x.y; r.z += x.z; r.w += x.w;
        }
        *(float4*)(out + ((size_t)b * TD + t0 + t) * HD + hh) = r;
    }
}

extern "C" void kernel_launch(void* const* d_in, const int* in_sizes, int n_in,
                              void* d_out, int out_size, void* d_ws, size_t ws_size,
                              hipStream_t stream) {
    const float* query = (const float*)d_in[0];
    const float* enc   = (const float*)d_in[1];
    const int*   lens  = (const int*)d_in[2];
    const float* W_h   = (const float*)d_in[3];
    const float* W_s   = (const float*)d_in[4];
    const float* v     = (const float*)d_in[5];
    float* out = (float*)d_out;

    char* ws = (char*)d_ws;
    float* encT = (float*)(ws);                       // 4 MB (B,H,S)  E_e
    float* qryf = (float*)(ws + ((size_t)4 << 20));   // 4 MB (B,T,H)  E_q

    void* args[] = {
        (void*)&enc, (void*)&query, (void*)&W_h, (void*)&W_s,
        (void*)&v, (void*)&lens, (void*)&encT, (void*)&qryf, (void*)&out
    };

    // Tier 1: grid 512 x 1024 threads (8 waves/SIMD). Host-side occupancy pre-screen.
    int nb = 0;
    hipError_t oerr = hipOccupancyMaxActiveBlocksPerMultiprocessor(
        &nb, (const void*)fusedT, 1024, 0);
    if (oerr == hipSuccess && nb >= 2) {
        hipError_t lerr = hipLaunchCooperativeKernel((const void*)fusedT,
                                                     dim3(512), dim3(1024), args, 0, stream);
        if (lerr == hipSuccess) return;
    }

    // Tier 2: proven grid-512 x 512 kernel (r2 config, ~102 us).
    nb = 0;
    oerr = hipOccupancyMaxActiveBlocksPerMultiprocessor(
        &nb, (const void*)fused512, 512, 0);
    if (oerr == hipSuccess && nb >= 2) {
        hipError_t lerr = hipLaunchCooperativeKernel((const void*)fused512,
                                                     dim3(512), dim3(512), args, 0, stream);
        if (lerr == hipSuccess) return;
    }

    // Tier 3: proven two-kernel path.
    dim3 pgrid(HD / 64, 64);
    proj_fb<<<pgrid, 256, 0, stream>>>(enc, query, W_h, W_s, encT, qryf);
    attn_fb<<<BD * (TD / 4), 512, 0, stream>>>(enc, encT, qryf, v, lens, out);
}

// Round 5
// 121.062 us; speedup vs baseline: 1.0060x; 1.0060x over previous
//
#include <hip/hip_runtime.h>
#include <hip/hip_cooperative_groups.h>
#include <cstddef>
#include <math.h>

namespace cg = cooperative_groups;

#define BD 8
#define TD 256
#define SD 256
#define HD 512
#define K2F 2.885390081777927f    // 2*log2(e): arg of exp2 for e^(2x)

#define EXP2(x) __builtin_amdgcn_exp2f(x)
#define RCP(x)  __builtin_amdgcn_rcpf(x)

typedef __attribute__((ext_vector_type(8))) _Float16 half8;
typedef __attribute__((ext_vector_type(4))) _Float16 half4;
typedef __attribute__((ext_vector_type(4))) float float4v;

// exp2 with arg clamped so E in [2^-80, 2^80]: products overflow to inf -> rcp -> 0,
// underflow to 0 -> r = 1; no inf*0 NaN path possible.
__device__ __forceinline__ float exp2_sat(float x) {
    return EXP2(fminf(fmaxf(x, -80.0f), 80.0f));
}

#define LSTR 40   // LDS row stride (halves) for proj staging

// ================= PHASE A, 512-thread variant (proven r2 code) =================
__device__ __forceinline__ void phaseA(
    int bid, int tid, float* smem,
    const float* __restrict__ enc, const float* __restrict__ qry,
    const float* __restrict__ Wh,  const float* __restrict__ Ws,
    float* __restrict__ encT, float* __restrict__ qryf)
{
    const int l  = tid & 63;
    const int w  = tid >> 6;
    const int rf = l & 15;
    const int q  = l >> 4;

    _Float16* LA = (_Float16*)smem;            // 64*40 halves = 5120 B
    _Float16* LB = (_Float16*)(smem + 1280);   // +5120 B

    const int x  = bid & 7;                    // XCD / owning batch
    const int k  = bid >> 3;                   // 0..63
    const bool isq = k >= 32;
    const int kk = k & 31;                     // 0..31
    const int my = (isq ? 32 : 0) + x * 4 + (kk & 3);
    const int n0 = (kk >> 2) * 64;
    const int m0 = my * 64;                    // stacked row 0..4095

    const int srow = tid >> 3;                 // staging row 0..63
    const int scol = (tid & 7) * 4;            // staging col (floats)
    const float* Abase = isq
        ? qry + (size_t)(m0 - 2048 + srow) * HD + scol
        : enc + (size_t)(m0 + srow) * HD + scol;
    const float* Bbase = (isq ? Ws : Wh) + (size_t)(n0 + srow) * HD + scol;

    const int mi = (w & 3) * 16;               // wave row-strip
    const int ni = (w >> 2) * 32;              // wave col-strip (2 MFMA tiles)

    float4v acc[2] = {{0,0,0,0},{0,0,0,0}};

    float4 a0 = *(const float4*)(Abase);
    float4 b0 = *(const float4*)(Bbase);

    for (int ks = 0; ks < 16; ++ks) {
        if (ks) __syncthreads();
        {
            half4 ha, hb;
            ha[0]=(_Float16)a0.x; ha[1]=(_Float16)a0.y; ha[2]=(_Float16)a0.z; ha[3]=(_Float16)a0.w;
            hb[0]=(_Float16)b0.x; hb[1]=(_Float16)b0.y; hb[2]=(_Float16)b0.z; hb[3]=(_Float16)b0.w;
            *(half4*)&LA[srow * LSTR + scol] = ha;
            *(half4*)&LB[srow * LSTR + scol] = hb;
        }
        __syncthreads();
        if (ks + 1 < 16) {
            const int ko = (ks + 1) * 32;
            a0 = *(const float4*)(Abase + ko);
            b0 = *(const float4*)(Bbase + ko);
        }
        half8 ah = *(const half8*)&LA[(mi + rf) * LSTR + q * 8];
        #pragma unroll
        for (int j = 0; j < 2; ++j) {
            half8 bh = *(const half8*)&LB[(ni + j * 16 + rf) * LSTR + q * 8];
            acc[j] = __builtin_amdgcn_mfma_f32_16x16x32_f16(ah, bh, acc[j], 0, 0, 0);
        }
    }

    // Epilogue (verified map: m-local = mi + q*4 + r, n-local = ni + j*16 + rf).
    if (!isq) {
        const int b  = m0 >> 8;                // == x by construction
        const int sb = (m0 & 255) + mi + q * 4;
        float* base = encT + (size_t)b * HD * SD;
        #pragma unroll
        for (int j = 0; j < 2; ++j) {
            float4 o = make_float4(exp2_sat(acc[j][0]*K2F), exp2_sat(acc[j][1]*K2F),
                                   exp2_sat(acc[j][2]*K2F), exp2_sat(acc[j][3]*K2F));
            *(float4*)(base + (size_t)(n0 + ni + j * 16 + rf) * SD + sb) = o;
        }
    } else {
        const int mrow = (m0 - 2048) + mi + q * 4;
        #pragma unroll
        for (int j = 0; j < 2; ++j)
            #pragma unroll
            for (int r = 0; r < 4; ++r)
                qryf[(size_t)(mrow + r) * HD + n0 + ni + j * 16 + rf] =
                    exp2_sat(acc[j][r] * K2F);
    }
}

// ================= PHASE A, 1024-thread variant (R4-verified: absmax identical) ==========
// Same 64x64 tile per block id (x=bid&7, k=bid>>3), same LSTR LDS layout, verified
// epilogue map. Threads 0-511 stage A tile, 512-1023 stage B tile; 1 MFMA/wave/ks.
__device__ __forceinline__ void phaseA1024(
    int bid, int tid, float* smem,
    const float* __restrict__ enc, const float* __restrict__ qry,
    const float* __restrict__ Wh,  const float* __restrict__ Ws,
    float* __restrict__ encT, float* __restrict__ qryf)
{
    const int l  = tid & 63;
    const int w  = tid >> 6;                   // wave 0..15
    const int rf = l & 15;
    const int q  = l >> 4;

    _Float16* LA = (_Float16*)smem;            // 64*40 halves = 5120 B
    _Float16* LB = (_Float16*)(smem + 1280);   // +5120 B

    const int x  = bid & 7;                    // XCD / owning batch
    const int k  = bid >> 3;                   // 0..63
    const bool isq = k >= 32;
    const int kk = k & 31;                     // 0..31
    const int my = (isq ? 32 : 0) + x * 4 + (kk & 3);
    const int n0 = (kk >> 2) * 64;
    const int m0 = my * 64;                    // stacked row 0..4095

    const bool stagesA = (tid < 512);          // wave-uniform (waves 0-7 vs 8-15)
    const int srow = (tid >> 3) & 63;          // staging row 0..63
    const int scol = (tid & 7) * 4;            // staging col (floats)
    const float* Sbase = stagesA
        ? (isq ? qry + (size_t)(m0 - 2048 + srow) * HD
               : enc + (size_t)(m0 + srow) * HD) + scol
        : (isq ? Ws : Wh) + (size_t)(n0 + srow) * HD + scol;
    _Float16* Ldst = (stagesA ? LA : LB) + srow * LSTR + scol;

    const int mi = (w & 3) * 16;               // wave row-strip (4)
    const int ni = (w >> 2) * 16;              // wave col-strip (4)

    float4v acc = {0, 0, 0, 0};

    float4 a0 = *(const float4*)(Sbase);

    for (int ks = 0; ks < 16; ++ks) {
        if (ks) __syncthreads();
        {
            half4 ha;
            ha[0]=(_Float16)a0.x; ha[1]=(_Float16)a0.y; ha[2]=(_Float16)a0.z; ha[3]=(_Float16)a0.w;
            *(half4*)Ldst = ha;
        }
        __syncthreads();
        if (ks + 1 < 16) a0 = *(const float4*)(Sbase + (ks + 1) * 32);
        half8 ah = *(const half8*)&LA[(mi + rf) * LSTR + q * 8];
        half8 bh = *(const half8*)&LB[(ni + rf) * LSTR + q * 8];
        acc = __builtin_amdgcn_mfma_f32_16x16x32_f16(ah, bh, acc, 0, 0, 0);
    }

    // Epilogue (verified map: m-local = mi + q*4 + r, n-local = ni + rf).
    if (!isq) {
        const int b  = m0 >> 8;
        const int sb = (m0 & 255) + mi + q * 4;
        float* base = encT + (size_t)b * HD * SD;
        float4 o = make_float4(exp2_sat(acc[0]*K2F), exp2_sat(acc[1]*K2F),
                               exp2_sat(acc[2]*K2F), exp2_sat(acc[3]*K2F));
        *(float4*)(base + (size_t)(n0 + ni + rf) * SD + sb) = o;
    } else {
        const int mrow = (m0 - 2048) + mi + q * 4;
        #pragma unroll
        for (int r = 0; r < 4; ++r)
            qryf[(size_t)(mrow + r) * HD + n0 + ni + rf] = exp2_sat(acc[r] * K2F);
    }
}

// ================= PHASE B, 512-thread template (proven, used by fused512) =================
template<int TT>
__device__ __forceinline__ void phaseB(
    int b, int t0, int tid, float* smem,
    const float* __restrict__ enc, const float* __restrict__ encT,
    const float* __restrict__ qryf, const float* __restrict__ v,
    const int* __restrict__ lens, float* __restrict__ out)
{
    const int l = tid & 63;
    const int w = tid >> 6;

    float* qls = smem;               // [j][t] 512*TT floats
    float* pls = smem + 512 * TT;    // [slice(4)][t(TT)][s(256)]; aliased avred
    float* wls = smem + 1536 * TT;   // [t][s] 256*TT floats

    {
        const float* qf = qryf + ((size_t)b * TD + t0) * HD;
        #pragma unroll
        for (int t = 0; t < TT; ++t) qls[tid * TT + t] = qf[t * HD + tid];
    }
    __syncthreads();

    float a[TT][4];
    #pragma unroll
    for (int t = 0; t < TT; ++t)
        #pragma unroll
        for (int c = 0; c < 4; ++c) a[t][c] = 0.0f;
    {
        const float* ep = encT + (size_t)b * HD * SD + (size_t)(w * 64) * SD + l * 4;
        const int jbase = w * 64;
        #pragma unroll 4
        for (int jj = 0; jj < 64; ++jj) {
            float4 e = *(const float4*)(ep + (size_t)jj * SD);
            float vj = v[jbase + jj];
            float qv[TT];
            #pragma unroll
            for (int t = 0; t < TT; ++t) qv[t] = qls[(jbase + jj) * TT + t];
            float ev[4] = {e.x, e.y, e.z, e.w};
            #pragma unroll
            for (int t = 0; t < TT; ++t)
                #pragma unroll
                for (int c = 0; c < 4; ++c) {
                    float p = fmaf(ev[c], qv[t], 1.0f);
                    a[t][c] = fmaf(vj, RCP(p), a[t][c]);
                }
        }
    }
    if (w < 4) {
        #pragma unroll
        for (int t = 0; t < TT; ++t)
            *(float4*)&pls[(w * TT + t) * 256 + l * 4] =
                make_float4(a[t][0], a[t][1], a[t][2], a[t][3]);
    }
    __syncthreads();
    if (w >= 4) {
        #pragma unroll
        for (int t = 0; t < TT; ++t) {
            float4 c4 = *(const float4*)&pls[((w - 4) * TT + t) * 256 + l * 4];
            c4.x += a[t][0]; c4.y += a[t][1]; c4.z += a[t][2]; c4.w += a[t][3];
            *(float4*)&pls[((w - 4) * TT + t) * 256 + l * 4] = c4;
        }
    }
    __syncthreads();

    if (w < TT) {
        const int t = w;
        float p[4] = {0, 0, 0, 0};
        #pragma unroll
        for (int g = 0; g < 4; ++g) {
            float4 pp = *(const float4*)&pls[(g * TT + t) * 256 + l * 4];
            p[0] += pp.x; p[1] += pp.y; p[2] += pp.z; p[3] += pp.w;
        }
        const int len = lens[b];
        const int s0 = l * 4;
        float sc[4];
        #pragma unroll
        for (int c = 0; c < 4; ++c)
            sc[c] = (s0 + c < len) ? -2.0f * p[c] : -INFINITY;
        float mx = fmaxf(fmaxf(sc[0], sc[1]), fmaxf(sc[2], sc[3]));
        #pragma unroll
        for (int off = 32; off; off >>= 1) mx = fmaxf(mx, __shfl_xor(mx, off));
        float ex[4]; float sum = 0.0f;
        #pragma unroll
        for (int c = 0; c < 4; ++c) { ex[c] = __expf(sc[c] - mx); sum += ex[c]; }
        #pragma unroll
        for (int off = 32; off; off >>= 1) sum += __shfl_xor(sum, off);
        const float inv = RCP(sum);
        *(float4*)&wls[t * SD + s0] = make_float4(ex[0]*inv, ex[1]*inv, ex[2]*inv, ex[3]*inv);
    }
    __syncthreads();

    const int sg = tid >> 7;
    const int h4 = (tid & 127) * 4;
    float* avred = pls;
    float4 o[TT];
    #pragma unroll
    for (int t = 0; t < TT; ++t) o[t] = make_float4(0.f, 0.f, 0.f, 0.f);
    {
        const float* eb = enc + (size_t)b * SD * HD + h4;
        #pragma unroll 2
        for (int ss = 0; ss < 64; ++ss) {
            const int s = sg * 64 + ss;
            float4 evv = *(const float4*)(eb + (size_t)s * HD);
            float wt[TT];
            #pragma unroll
            for (int t = 0; t < TT; ++t) wt[t] = wls[t * SD + s];
            #pragma unroll
            for (int t = 0; t < TT; ++t) {
                o[t].x = fmaf(wt[t], evv.x, o[t].x);
                o[t].y = fmaf(wt[t], evv.y, o[t].y);
                o[t].z = fmaf(wt[t], evv.z, o[t].z);
                o[t].w = fmaf(wt[t], evv.w, o[t].w);
            }
        }
    }
    if (sg < 2) {
        #pragma unroll
        for (int t = 0; t < TT; ++t)
            *(float4*)&avred[(size_t)(sg * TT + t) * 512 + h4] = o[t];
    }
    __syncthreads();
    if (sg >= 2) {
        #pragma unroll
        for (int t = 0; t < TT; ++t) {
            float4 c4 = *(const float4*)&avred[(size_t)((sg - 2) * TT + t) * 512 + h4];
            c4.x += o[t].x; c4.y += o[t].y; c4.z += o[t].z; c4.w += o[t].w;
            *(float4*)&avred[(size_t)((sg - 2) * TT + t) * 512 + h4] = c4;
        }
    }
    __syncthreads();

    if (tid < TT * 128) {
        const int t  = tid >> 7;
        const int hh = (tid & 127) * 4;
        float4 x0 = *(const float4*)&avred[(size_t)(0 * TT + t) * 512 + hh];
        float4 x1 = *(const float4*)&avred[(size_t)(1 * TT + t) * 512 + hh];
        float4 r = make_float4(x0.x + x1.x, x0.y + x1.y, x0.z + x1.z, x0.w + x1.w);
        *(float4*)(out + ((size_t)b * TD + t0 + t) * HD + hh) = r;
    }
}

// ================= PHASE B, 1024-thread TT=8 (halves bytes/wave) =================
// smem: qls [8][512] 16 KB | pls [4][8][256] 32 KB (aliased avred [2][8][512]) | wls [8][256] 8 KB
// Wave w covers j-slice of 32 rows; 4-slot partial combine in 4 barrier stages.
__device__ __forceinline__ void phaseB1024(
    int b, int t0, int tid, float* smem,
    const float* __restrict__ enc, const float* __restrict__ encT,
    const float* __restrict__ qryf, const float* __restrict__ v,
    const int* __restrict__ lens, float* __restrict__ out)
{
    const int l = tid & 63;
    const int w = tid >> 6;          // 0..15

    float* qls = smem;               // [t][j] 8*512 floats
    float* pls = smem + 4096;        // [4][8][256] floats; aliased avred
    float* wls = smem + 12288;       // [8][256] floats

    {   // stage E_q: qls[t][j] (conflict-free writes, broadcast reads)
        const float* qf = qryf + ((size_t)b * TD + t0) * HD;
        const int j = tid & 511;
        #pragma unroll
        for (int t = (tid >> 9); t < 8; t += 2)
            qls[t * 512 + j] = qf[t * HD + j];
    }
    __syncthreads();

    // ---- scores: wave w covers j in [w*32, (w+1)*32); lane owns s = 4l..4l+3 ----
    float a[8][4];
    #pragma unroll
    for (int t = 0; t < 8; ++t)
        #pragma unroll
        for (int c = 0; c < 4; ++c) a[t][c] = 0.0f;
    {
        const int jbase = w * 32;
        const float* ep = encT + (size_t)b * HD * SD + (size_t)jbase * SD + l * 4;
        #pragma unroll 4
        for (int jj = 0; jj < 32; ++jj) {
            float4 e = *(const float4*)(ep + (size_t)jj * SD);  // coalesced 1 KB/wave
            float vj = v[jbase + jj];                           // uniform -> s_load
            float qv[8];
            #pragma unroll
            for (int t = 0; t < 8; ++t) qv[t] = qls[t * 512 + jbase + jj];  // broadcast
            float ev[4] = {e.x, e.y, e.z, e.w};
            #pragma unroll
            for (int t = 0; t < 8; ++t)
                #pragma unroll
                for (int c = 0; c < 4; ++c) {
                    float p = fmaf(ev[c], qv[t], 1.0f);
                    a[t][c] = fmaf(vj, RCP(p), a[t][c]);
                }
        }
    }
    // ---- 4-slot partial combine, 4 stages (slot g accumulates waves g, g+4, g+8, g+12) ----
    if (w < 4) {
        #pragma unroll
        for (int t = 0; t < 8; ++t)
            *(float4*)&pls[(w * 8 + t) * 256 + l * 4] =
                make_float4(a[t][0], a[t][1], a[t][2], a[t][3]);
    }
    __syncthreads();
    if (w >= 4 && w < 8) {
        #pragma unroll
        for (int t = 0; t < 8; ++t) {
            float4 c4 = *(const float4*)&pls[((w - 4) * 8 + t) * 256 + l * 4];
            c4.x += a[t][0]; c4.y += a[t][1]; c4.z += a[t][2]; c4.w += a[t][3];
            *(float4*)&pls[((w - 4) * 8 + t) * 256 + l * 4] = c4;
        }
    }
    __syncthreads();
    if (w >= 8 && w < 12) {
        #pragma unroll
        for (int t = 0; t < 8; ++t) {
            float4 c4 = *(const float4*)&pls[((w - 8) * 8 + t) * 256 + l * 4];
            c4.x += a[t][0]; c4.y += a[t][1]; c4.z += a[t][2]; c4.w += a[t][3];
            *(float4*)&pls[((w - 8) * 8 + t) * 256 + l * 4] = c4;
        }
    }
    __syncthreads();
    if (w >= 12) {
        #pragma unroll
        for (int t = 0; t < 8; ++t) {
            float4 c4 = *(const float4*)&pls[((w - 12) * 8 + t) * 256 + l * 4];
            c4.x += a[t][0]; c4.y += a[t][1]; c4.z += a[t][2]; c4.w += a[t][3];
            *(float4*)&pls[((w - 12) * 8 + t) * 256 + l * 4] = c4;
        }
    }
    __syncthreads();

    // ---- combine 4 slots + masked softmax: wave w<8 handles t=w; lane owns 4 s ----
    if (w < 8) {
        const int t = w;
        float p[4] = {0, 0, 0, 0};
        #pragma unroll
        for (int g = 0; g < 4; ++g) {
            float4 pp = *(const float4*)&pls[(g * 8 + t) * 256 + l * 4];
            p[0] += pp.x; p[1] += pp.y; p[2] += pp.z; p[3] += pp.w;
        }
        const int len = lens[b];
        const int s0 = l * 4;
        float sc[4];
        #pragma unroll
        for (int c = 0; c < 4; ++c)
            sc[c] = (s0 + c < len) ? -2.0f * p[c] : -INFINITY;
        float mx = fmaxf(fmaxf(sc[0], sc[1]), fmaxf(sc[2], sc[3]));
        #pragma unroll
        for (int off = 32; off; off >>= 1) mx = fmaxf(mx, __shfl_xor(mx, off));
        float ex[4]; float sum = 0.0f;
        #pragma unroll
        for (int c = 0; c < 4; ++c) { ex[c] = __expf(sc[c] - mx); sum += ex[c]; }
        #pragma unroll
        for (int off = 32; off; off >>= 1) sum += __shfl_xor(sum, off);
        const float inv = RCP(sum);
        *(float4*)&wls[t * SD + s0] = make_float4(ex[0]*inv, ex[1]*inv, ex[2]*inv, ex[3]*inv);
    }
    __syncthreads();

    // ---- AV: thread owns (h-float4, s-slice sg of 32); accumulates all 8 t ----
    const int sg = tid >> 7;          // 0..7 (wave-pair-uniform)
    const int h4 = (tid & 127) * 4;
    float* avred = pls;               // [2][8][512] = 8192 floats
    float4 o[8];
    #pragma unroll
    for (int t = 0; t < 8; ++t) o[t] = make_float4(0.f, 0.f, 0.f, 0.f);
    {
        const float* eb = enc + (size_t)b * SD * HD + h4;
        #pragma unroll 2
        for (int ss = 0; ss < 32; ++ss) {
            const int s = sg * 32 + ss;
            float4 evv = *(const float4*)(eb + (size_t)s * HD);
            float wt[8];
            #pragma unroll
            for (int t = 0; t < 8; ++t) wt[t] = wls[t * SD + s];  // broadcast
            #pragma unroll
            for (int t = 0; t < 8; ++t) {
                o[t].x = fmaf(wt[t], evv.x, o[t].x);
                o[t].y = fmaf(wt[t], evv.y, o[t].y);
                o[t].z = fmaf(wt[t], evv.z, o[t].z);
                o[t].w = fmaf(wt[t], evv.w, o[t].w);
            }
        }
    }
    // 2-slot reduce in 4 stages (slot g accumulates sg = g, g+2, g+4, g+6)
    if (sg < 2) {
        #pragma unroll
        for (int t = 0; t < 8; ++t)
            *(float4*)&avred[(size_t)(sg * 8 + t) * 512 + h4] = o[t];
    }
    __syncthreads();
    if (sg >= 2 && sg < 4) {
        #pragma unroll
        for (int t = 0; t < 8; ++t) {
            float4 c4 = *(const float4*)&avred[(size_t)((sg - 2) * 8 + t) * 512 + h4];
            c4.x += o[t].x; c4.y += o[t].y; c4.z += o[t].z; c4.w += o[t].w;
            *(float4*)&avred[(size_t)((sg - 2) * 8 + t) * 512 + h4] = c4;
        }
    }
    __syncthreads();
    if (sg >= 4 && sg < 6) {
        #pragma unroll
        for (int t = 0; t < 8; ++t) {
            float4 c4 = *(const float4*)&avred[(size_t)((sg - 4) * 8 + t) * 512 + h4];
            c4.x += o[t].x; c4.y += o[t].y; c4.z += o[t].z; c4.w += o[t].w;
            *(float4*)&avred[(size_t)((sg - 4) * 8 + t) * 512 + h4] = c4;
        }
    }
    __syncthreads();
    if (sg >= 6) {
        #pragma unroll
        for (int t = 0; t < 8; ++t) {
            float4 c4 = *(const float4*)&avred[(size_t)((sg - 6) * 8 + t) * 512 + h4];
            c4.x += o[t].x; c4.y += o[t].y; c4.z += o[t].z; c4.w += o[t].w;
            *(float4*)&avred[(size_t)((sg - 6) * 8 + t) * 512 + h4] = c4;
        }
    }
    __syncthreads();

    // final reduce + store: thread owns (t = tid>>7 in 0..7, h-float4)
    {
        const int t  = tid >> 7;
        const int hh = (tid & 127) * 4;
        float4 x0 = *(const float4*)&avred[(size_t)(0 * 8 + t) * 512 + hh];
        float4 x1 = *(const float4*)&avred[(size_t)(1 * 8 + t) * 512 + hh];
        float4 r = make_float4(x0.x + x1.x, x0.y + x1.y, x0.z + x1.z, x0.w + x1.w);
        *(float4*)(out + ((size_t)b * TD + t0 + t) * HD + hh) = r;
    }
}

// ============ fusedW: grid 256 x 1024 threads. TT=8 -> bytes/wave halved ============
// Phase A: two 64x64 tiles per block (bid, bid+256), R4-verified phaseA1024.
// Phase B: TT=8, 16 waves, 56 KB LDS, 1 block/CU, XCD pinning (b = bid & 7).
__global__ __launch_bounds__(1024, 4) void fusedW(
    const float* __restrict__ enc, const float* __restrict__ qry,
    const float* __restrict__ Wh,  const float* __restrict__ Ws,
    const float* __restrict__ v,   const int* __restrict__ lens,
    float* __restrict__ encT, float* __restrict__ qryf, float* __restrict__ out)
{
    __shared__ float smem[14336];   // 56 KB
    const int bid = blockIdx.x;     // 0..255
    const int tid = threadIdx.x;

    phaseA1024(bid, tid, smem, enc, qry, Wh, Ws, encT, qryf);
    __syncthreads();
    phaseA1024(bid + 256, tid, smem, enc, qry, Wh, Ws, encT, qryf);

    cg::this_grid().sync();

    phaseB1024(bid & 7, (bid >> 3) * 8, tid, smem, enc, encT, qryf, v, lens, out);
}

// ============ fused512: proven r2 config (~102 us), 28 KB LDS ============
__global__ __launch_bounds__(512) void fused512(
    const float* __restrict__ enc, const float* __restrict__ qry,
    const float* __restrict__ Wh,  const float* __restrict__ Ws,
    const float* __restrict__ v,   const int* __restrict__ lens,
    float* __restrict__ encT, float* __restrict__ qryf, float* __restrict__ out)
{
    __shared__ float smem[7168];   // 28 KB
    const int bid = blockIdx.x;
    phaseA(bid, threadIdx.x, smem, enc, qry, Wh, Ws, encT, qryf);
    cg::this_grid().sync();
    phaseB<4>(bid & 7, (bid >> 3) * 4, threadIdx.x, smem,
              enc, encT, qryf, v, lens, out);
}

// ================= fallback pair (proven R8 proj + R7 attn) =================
__global__ __launch_bounds__(256) void proj_fb(
    const float* __restrict__ enc, const float* __restrict__ qry,
    const float* __restrict__ Wh,  const float* __restrict__ Ws,
    float* __restrict__ encT, float* __restrict__ qryf)
{
    __shared__ _Float16 LA[64 * LSTR], LB[64 * LSTR];

    const int tid = threadIdx.x;
    const int l = tid & 63, w = tid >> 6;
    const int rf = l & 15, q = l >> 4;
    const int my = blockIdx.y;
    const bool isq = my >= 32;
    const int m0 = my * 64;
    const int n0 = blockIdx.x * 64;

    const int srow = tid >> 2;
    const int scol = (tid & 3) * 8;
    const float* Abase = isq
        ? qry + (size_t)(m0 - 2048 + srow) * HD + scol
        : enc + (size_t)(m0 + srow) * HD + scol;
    const float* Bbase = (isq ? Ws : Wh) + (size_t)(n0 + srow) * HD + scol;

    const int mi = (w & 1) * 32, ni = (w >> 1) * 32;
    float4v acc[2][2] = {{{0,0,0,0},{0,0,0,0}},{{0,0,0,0},{0,0,0,0}}};

    float4 a0 = *(const float4*)(Abase);
    float4 a1 = *(const float4*)(Abase + 4);
    float4 b0 = *(const float4*)(Bbase);
    float4 b1 = *(const float4*)(Bbase + 4);

    for (int ks = 0; ks < 16; ++ks) {
        if (ks) __syncthreads();
        {
            float af[8] = {a0.x,a0.y,a0.z,a0.w,a1.x,a1.y,a1.z,a1.w};
            float bf[8] = {b0.x,b0.y,b0.z,b0.w,b1.x,b1.y,b1.z,b1.w};
            half8 ha, hb;
            #pragma unroll
            for (int i = 0; i < 8; ++i) { ha[i] = (_Float16)af[i]; hb[i] = (_Float16)bf[i]; }
            *(half8*)&LA[srow * LSTR + scol] = ha;
            *(half8*)&LB[srow * LSTR + scol] = hb;
        }
        __syncthreads();
        if (ks + 1 < 16) {
            const int ko = (ks + 1) * 32;
            a0 = *(const float4*)(Abase + ko);
            a1 = *(const float4*)(Abase + ko + 4);
            b0 = *(const float4*)(Bbase + ko);
            b1 = *(const float4*)(Bbase + ko + 4);
        }
        half8 ah[2], bh[2];
        #pragma unroll
        for (int i = 0; i < 2; ++i) {
            ah[i] = *(const half8*)&LA[(mi + i * 16 + rf) * LSTR + q * 8];
            bh[i] = *(const half8*)&LB[(ni + i * 16 + rf) * LSTR + q * 8];
        }
        #pragma unroll
        for (int i = 0; i < 2; ++i)
            #pragma unroll
            for (int j = 0; j < 2; ++j)
                acc[i][j] = __builtin_amdgcn_mfma_f32_16x16x32_f16(ah[i], bh[j], acc[i][j], 0, 0, 0);
    }

    if (!isq) {
        const int b  = m0 >> 8;
        const int sb = (m0 & 255) + mi + q * 4;
        float* base = encT + (size_t)b * HD * SD;
        #pragma unroll
        for (int i = 0; i < 2; ++i)
            #pragma unroll
            for (int j = 0; j < 2; ++j) {
                float4 o = make_float4(exp2_sat(acc[i][j][0]*K2F), exp2_sat(acc[i][j][1]*K2F),
                                       exp2_sat(acc[i][j][2]*K2F), exp2_sat(acc[i][j][3]*K2F));
                *(float4*)(base + (size_t)(n0 + ni + j * 16 + rf) * SD + sb + i * 16) = o;
            }
    } else {
        const int mrow = (m0 - 2048) + mi + q * 4;
        #pragma unroll
        for (int i = 0; i < 2; ++i)
            #pragma unroll
            for (int j = 0; j < 2; ++j)
                #pragma unroll
                for (int r = 0; r < 4; ++r)
                    qryf[(size_t)(mrow + i * 16 + r) * HD + n0 + ni + j * 16 + rf] =
                        exp2_sat(acc[i][j][r] * K2F);
    }
}

__global__ __launch_bounds__(512) void attn_fb(
    const float* __restrict__ enc, const float* __restrict__ encT,
    const float* __restrict__ qryf, const float* __restrict__ v,
    const int* __restrict__ lens, float* __restrict__ out)
{
    __shared__ float qls[HD * 4];
    __shared__ float pls[8 * 4 * 256];
    __shared__ float wls[4 * SD];

    const int blk = blockIdx.x;
    const int b   = blk >> 6;
    const int t0  = (blk & 63) * 4;
    const int tid = threadIdx.x;
    const int w   = tid >> 6;
    const int l   = tid & 63;

    {
        const float* qf = qryf + ((size_t)b * TD + t0) * HD;
        float4 qv;
        qv.x = qf[0 * HD + tid]; qv.y = qf[1 * HD + tid];
        qv.z = qf[2 * HD + tid]; qv.w = qf[3 * HD + tid];
        *(float4*)&qls[tid * 4] = qv;
    }
    __syncthreads();

    float a[4][4];
    #pragma unroll
    for (int t = 0; t < 4; ++t)
        #pragma unroll
        for (int c = 0; c < 4; ++c) a[t][c] = 0.0f;
    {
        const float* ep = encT + (size_t)b * HD * SD + (size_t)(w * 64) * SD + l * 4;
        const int jbase = w * 64;
        #pragma unroll 4
        for (int jj = 0; jj < 64; ++jj) {
            float4 e = *(const float4*)(ep + (size_t)jj * SD);
            float4 q4 = *(const float4*)&qls[(jbase + jj) * 4];
            float vj = v[jbase + jj];
            float ev[4] = {e.x, e.y, e.z, e.w};
            float qv[4] = {q4.x, q4.y, q4.z, q4.w};
            #pragma unroll
            for (int t = 0; t < 4; ++t)
                #pragma unroll
                for (int c = 0; c < 4; ++c) {
                    float p = fmaf(ev[c], qv[t], 1.0f);
                    a[t][c] = fmaf(vj, RCP(p), a[t][c]);
                }
        }
    }
    #pragma unroll
    for (int t = 0; t < 4; ++t)
        *(float4*)&pls[(w * 4 + t) * 256 + l * 4] = make_float4(a[t][0], a[t][1], a[t][2], a[t][3]);
    __syncthreads();

    if (w < 4) {
        const int t = w;
        float p[4] = {0, 0, 0, 0};
        #pragma unroll
        for (int g = 0; g < 8; ++g) {
            float4 pp = *(const float4*)&pls[(g * 4 + t) * 256 + l * 4];
            p[0] += pp.x; p[1] += pp.y; p[2] += pp.z; p[3] += pp.w;
        }
        const int len = lens[b];
        const int s0 = l * 4;
        float sc[4];
        #pragma unroll
        for (int c = 0; c < 4; ++c)
            sc[c] = (s0 + c < len) ? -2.0f * p[c] : -INFINITY;
        float mx = fmaxf(fmaxf(sc[0], sc[1]), fmaxf(sc[2], sc[3]));
        #pragma unroll
        for (int off = 32; off; off >>= 1) mx = fmaxf(mx, __shfl_xor(mx, off));
        float ex[4]; float sum = 0.0f;
        #pragma unroll
        for (int c = 0; c < 4; ++c) { ex[c] = __expf(sc[c] - mx); sum += ex[c]; }
        #pragma unroll
        for (int off = 32; off; off >>= 1) sum += __shfl_xor(sum, off);
        const float inv = RCP(sum);
        *(float4*)&wls[t * SD + s0] = make_float4(ex[0]*inv, ex[1]*inv, ex[2]*inv, ex[3]*inv);
    }
    __syncthreads();

    const int g  = tid >> 7;
    const int h4 = (tid & 127) * 4;
    float* avred = pls;
    {
        const float* eb = enc + (size_t)b * SD * HD + h4;
        float4 o[4] = {{0,0,0,0},{0,0,0,0},{0,0,0,0},{0,0,0,0}};
        #pragma unroll 2
        for (int ss = 0; ss < 64; ++ss) {
            const int s = g * 64 + ss;
            float4 evv = *(const float4*)(eb + (size_t)s * HD);
            float wt[4];
            #pragma unroll
            for (int t = 0; t < 4; ++t) wt[t] = wls[t * SD + s];
            #pragma unroll
            for (int t = 0; t < 4; ++t) {
                o[t].x = fmaf(wt[t], evv.x, o[t].x);
                o[t].y = fmaf(wt[t], evv.y, o[t].y);
                o[t].z = fmaf(wt[t], evv.z, o[t].z);
                o[t].w = fmaf(wt[t], evv.w, o[t].w);
            }
        }
        #pragma unroll
        for (int t = 0; t < 4; ++t)
            *(float4*)&avred[(size_t)(g * 4 + t) * 512 + h4] = o[t];
    }
    __syncthreads();
    {
        const int t  = tid >> 7;
        const int hh = (tid & 127) * 4;
        float4 r = {0, 0, 0, 0};
        #pragma unroll
        for (int gg = 0; gg < 4; ++gg) {
            float4 x = *(const float4*)&avred[(size_t)(gg * 4 + t) * 512 + hh];
            r.x += x.x; r.y += x.y; r.z += x.z; r.w += x.w;
        }
        *(float4*)(out + ((size_t)b * TD + t0 + t) * HD + hh) = r;
    }
}

extern "C" void kernel_launch(void* const* d_in, const int* in_sizes, int n_in,
                              void* d_out, int out_size, void* d_ws, size_t ws_size,
                              hipStream_t stream) {
    const float* query = (const float*)d_in[0];
    const float* enc   = (const float*)d_in[1];
    const int*   lens  = (const int*)d_in[2];
    const float* W_h   = (const float*)d_in[3];
    const float* W_s   = (const float*)d_in[4];
    const float* v     = (const float*)d_in[5];
    float* out = (float*)d_out;

    char* ws = (char*)d_ws;
    float* encT = (float*)(ws);                       // 4 MB (B,H,S)  E_e
    float* qryf = (float*)(ws + ((size_t)4 << 20));   // 4 MB (B,T,H)  E_q

    void* args[] = {
        (void*)&enc, (void*)&query, (void*)&W_h, (void*)&W_s,
        (void*)&v, (void*)&lens, (void*)&encT, (void*)&qryf, (void*)&out
    };

    // Tier 1: grid 256 x 1024 threads, TT=8 (halved bytes/wave). Pre-screen occupancy.
    int nb = 0;
    hipError_t oerr = hipOccupancyMaxActiveBlocksPerMultiprocessor(
        &nb, (const void*)fusedW, 1024, 0);
    if (oerr == hipSuccess && nb >= 1) {
        hipError_t lerr = hipLaunchCooperativeKernel((const void*)fusedW,
                                                     dim3(256), dim3(1024), args, 0, stream);
        if (lerr == hipSuccess) return;
    }

    // Tier 2: proven grid-512 x 512 kernel (r2 config, ~102 us).
    nb = 0;
    oerr = hipOccupancyMaxActiveBlocksPerMultiprocessor(
        &nb, (const void*)fused512, 512, 0);
    if (oerr == hipSuccess && nb >= 2) {
        hipError_t lerr = hipLaunchCooperativeKernel((const void*)fused512,
                                                     dim3(512), dim3(512), args, 0, stream);
        if (lerr == hipSuccess) return;
    }

    // Tier 3: proven two-kernel path.
    dim3 pgrid(HD / 64, 64);
    proj_fb<<<pgrid, 256, 0, stream>>>(enc, query, W_h, W_s, encT, qryf);
    attn_fb<<<BD * (TD / 4), 512, 0, stream>>>(enc, encT, qryf, v, lens, out);
}

// Round 6
// 120.958 us; speedup vs baseline: 1.0068x; 1.0009x over previous
//
#include <hip/hip_runtime.h>
#include <hip/hip_cooperative_groups.h>
#include <cstddef>
#include <math.h>

namespace cg = cooperative_groups;

#define BD 8
#define TD 256
#define SD 256
#define HD 512
#define K2F 2.885390081777927f    // 2*log2(e): arg of exp2 for e^(2x)

#define EXP2(x) __builtin_amdgcn_exp2f(x)
#define RCP(x)  __builtin_amdgcn_rcpf(x)

typedef __attribute__((ext_vector_type(8))) _Float16 half8;
typedef __attribute__((ext_vector_type(4))) _Float16 half4;
typedef __attribute__((ext_vector_type(4))) float float4v;

// exp2 with arg clamped so E in [2^-80, 2^80]: products overflow to inf -> rcp -> 0,
// underflow to 0 -> r = 1; no inf*0 NaN path possible.
__device__ __forceinline__ float exp2_sat(float x) {
    return EXP2(fminf(fmaxf(x, -80.0f), 80.0f));
}

#define LSTR 40   // LDS row stride (halves) for proj staging

// ================= PHASE A, 512-thread variant (proven r2 code) =================
__device__ __forceinline__ void phaseA(
    int bid, int tid, float* smem,
    const float* __restrict__ enc, const float* __restrict__ qry,
    const float* __restrict__ Wh,  const float* __restrict__ Ws,
    float* __restrict__ encT, float* __restrict__ qryf)
{
    const int l  = tid & 63;
    const int w  = tid >> 6;
    const int rf = l & 15;
    const int q  = l >> 4;

    _Float16* LA = (_Float16*)smem;            // 64*40 halves = 5120 B
    _Float16* LB = (_Float16*)(smem + 1280);   // +5120 B

    const int x  = bid & 7;                    // XCD / owning batch
    const int k  = bid >> 3;                   // 0..63
    const bool isq = k >= 32;
    const int kk = k & 31;                     // 0..31
    const int my = (isq ? 32 : 0) + x * 4 + (kk & 3);
    const int n0 = (kk >> 2) * 64;
    const int m0 = my * 64;                    // stacked row 0..4095

    const int srow = tid >> 3;                 // staging row 0..63
    const int scol = (tid & 7) * 4;            // staging col (floats)
    const float* Abase = isq
        ? qry + (size_t)(m0 - 2048 + srow) * HD + scol
        : enc + (size_t)(m0 + srow) * HD + scol;
    const float* Bbase = (isq ? Ws : Wh) + (size_t)(n0 + srow) * HD + scol;

    const int mi = (w & 3) * 16;               // wave row-strip
    const int ni = (w >> 2) * 32;              // wave col-strip (2 MFMA tiles)

    float4v acc[2] = {{0,0,0,0},{0,0,0,0}};

    float4 a0 = *(const float4*)(Abase);
    float4 b0 = *(const float4*)(Bbase);

    for (int ks = 0; ks < 16; ++ks) {
        if (ks) __syncthreads();
        {
            half4 ha, hb;
            ha[0]=(_Float16)a0.x; ha[1]=(_Float16)a0.y; ha[2]=(_Float16)a0.z; ha[3]=(_Float16)a0.w;
            hb[0]=(_Float16)b0.x; hb[1]=(_Float16)b0.y; hb[2]=(_Float16)b0.z; hb[3]=(_Float16)b0.w;
            *(half4*)&LA[srow * LSTR + scol] = ha;
            *(half4*)&LB[srow * LSTR + scol] = hb;
        }
        __syncthreads();
        if (ks + 1 < 16) {
            const int ko = (ks + 1) * 32;
            a0 = *(const float4*)(Abase + ko);
            b0 = *(const float4*)(Bbase + ko);
        }
        half8 ah = *(const half8*)&LA[(mi + rf) * LSTR + q * 8];
        #pragma unroll
        for (int j = 0; j < 2; ++j) {
            half8 bh = *(const half8*)&LB[(ni + j * 16 + rf) * LSTR + q * 8];
            acc[j] = __builtin_amdgcn_mfma_f32_16x16x32_f16(ah, bh, acc[j], 0, 0, 0);
        }
    }

    // Epilogue (verified map: m-local = mi + q*4 + r, n-local = ni + j*16 + rf).
    if (!isq) {
        const int b  = m0 >> 8;                // == x by construction
        const int sb = (m0 & 255) + mi + q * 4;
        float* base = encT + (size_t)b * HD * SD;
        #pragma unroll
        for (int j = 0; j < 2; ++j) {
            float4 o = make_float4(exp2_sat(acc[j][0]*K2F), exp2_sat(acc[j][1]*K2F),
                                   exp2_sat(acc[j][2]*K2F), exp2_sat(acc[j][3]*K2F));
            *(float4*)(base + (size_t)(n0 + ni + j * 16 + rf) * SD + sb) = o;
        }
    } else {
        const int mrow = (m0 - 2048) + mi + q * 4;
        #pragma unroll
        for (int j = 0; j < 2; ++j)
            #pragma unroll
            for (int r = 0; r < 4; ++r)
                qryf[(size_t)(mrow + r) * HD + n0 + ni + j * 16 + rf] =
                    exp2_sat(acc[j][r] * K2F);
    }
}

// ================= PHASE A, 1024-thread variant (R4/R5-verified: absmax identical) ========
__device__ __forceinline__ void phaseA1024(
    int bid, int tid, float* smem,
    const float* __restrict__ enc, const float* __restrict__ qry,
    const float* __restrict__ Wh,  const float* __restrict__ Ws,
    float* __restrict__ encT, float* __restrict__ qryf)
{
    const int l  = tid & 63;
    const int w  = tid >> 6;                   // wave 0..15
    const int rf = l & 15;
    const int q  = l >> 4;

    _Float16* LA = (_Float16*)smem;            // 64*40 halves = 5120 B
    _Float16* LB = (_Float16*)(smem + 1280);   // +5120 B

    const int x  = bid & 7;                    // XCD / owning batch
    const int k  = bid >> 3;                   // 0..63
    const bool isq = k >= 32;
    const int kk = k & 31;                     // 0..31
    const int my = (isq ? 32 : 0) + x * 4 + (kk & 3);
    const int n0 = (kk >> 2) * 64;
    const int m0 = my * 64;                    // stacked row 0..4095

    const bool stagesA = (tid < 512);          // wave-uniform (waves 0-7 vs 8-15)
    const int srow = (tid >> 3) & 63;          // staging row 0..63
    const int scol = (tid & 7) * 4;            // staging col (floats)
    const float* Sbase = stagesA
        ? (isq ? qry + (size_t)(m0 - 2048 + srow) * HD
               : enc + (size_t)(m0 + srow) * HD) + scol
        : (isq ? Ws : Wh) + (size_t)(n0 + srow) * HD + scol;
    _Float16* Ldst = (stagesA ? LA : LB) + srow * LSTR + scol;

    const int mi = (w & 3) * 16;               // wave row-strip (4)
    const int ni = (w >> 2) * 16;              // wave col-strip (4)

    float4v acc = {0, 0, 0, 0};

    float4 a0 = *(const float4*)(Sbase);

    for (int ks = 0; ks < 16; ++ks) {
        if (ks) __syncthreads();
        {
            half4 ha;
            ha[0]=(_Float16)a0.x; ha[1]=(_Float16)a0.y; ha[2]=(_Float16)a0.z; ha[3]=(_Float16)a0.w;
            *(half4*)Ldst = ha;
        }
        __syncthreads();
        if (ks + 1 < 16) a0 = *(const float4*)(Sbase + (ks + 1) * 32);
        half8 ah = *(const half8*)&LA[(mi + rf) * LSTR + q * 8];
        half8 bh = *(const half8*)&LB[(ni + rf) * LSTR + q * 8];
        acc = __builtin_amdgcn_mfma_f32_16x16x32_f16(ah, bh, acc, 0, 0, 0);
    }

    // Epilogue (verified map: m-local = mi + q*4 + r, n-local = ni + rf).
    if (!isq) {
        const int b  = m0 >> 8;
        const int sb = (m0 & 255) + mi + q * 4;
        float* base = encT + (size_t)b * HD * SD;
        float4 o = make_float4(exp2_sat(acc[0]*K2F), exp2_sat(acc[1]*K2F),
                               exp2_sat(acc[2]*K2F), exp2_sat(acc[3]*K2F));
        *(float4*)(base + (size_t)(n0 + ni + rf) * SD + sb) = o;
    } else {
        const int mrow = (m0 - 2048) + mi + q * 4;
        #pragma unroll
        for (int r = 0; r < 4; ++r)
            qryf[(size_t)(mrow + r) * HD + n0 + ni + rf] = exp2_sat(acc[r] * K2F);
    }
}

// ================= PHASE B, 512-thread template (proven, used by fused512) =================
template<int TT>
__device__ __forceinline__ void phaseB(
    int b, int t0, int tid, float* smem,
    const float* __restrict__ enc, const float* __restrict__ encT,
    const float* __restrict__ qryf, const float* __restrict__ v,
    const int* __restrict__ lens, float* __restrict__ out)
{
    const int l = tid & 63;
    const int w = tid >> 6;

    float* qls = smem;               // [j][t] 512*TT floats
    float* pls = smem + 512 * TT;    // [slice(4)][t(TT)][s(256)]; aliased avred
    float* wls = smem + 1536 * TT;   // [t][s] 256*TT floats

    {
        const float* qf = qryf + ((size_t)b * TD + t0) * HD;
        #pragma unroll
        for (int t = 0; t < TT; ++t) qls[tid * TT + t] = qf[t * HD + tid];
    }
    __syncthreads();

    float a[TT][4];
    #pragma unroll
    for (int t = 0; t < TT; ++t)
        #pragma unroll
        for (int c = 0; c < 4; ++c) a[t][c] = 0.0f;
    {
        const float* ep = encT + (size_t)b * HD * SD + (size_t)(w * 64) * SD + l * 4;
        const int jbase = w * 64;
        #pragma unroll 4
        for (int jj = 0; jj < 64; ++jj) {
            float4 e = *(const float4*)(ep + (size_t)jj * SD);
            float vj = v[jbase + jj];
            float qv[TT];
            #pragma unroll
            for (int t = 0; t < TT; ++t) qv[t] = qls[(jbase + jj) * TT + t];
            float ev[4] = {e.x, e.y, e.z, e.w};
            #pragma unroll
            for (int t = 0; t < TT; ++t)
                #pragma unroll
                for (int c = 0; c < 4; ++c) {
                    float p = fmaf(ev[c], qv[t], 1.0f);
                    a[t][c] = fmaf(vj, RCP(p), a[t][c]);
                }
        }
    }
    if (w < 4) {
        #pragma unroll
        for (int t = 0; t < TT; ++t)
            *(float4*)&pls[(w * TT + t) * 256 + l * 4] =
                make_float4(a[t][0], a[t][1], a[t][2], a[t][3]);
    }
    __syncthreads();
    if (w >= 4) {
        #pragma unroll
        for (int t = 0; t < TT; ++t) {
            float4 c4 = *(const float4*)&pls[((w - 4) * TT + t) * 256 + l * 4];
            c4.x += a[t][0]; c4.y += a[t][1]; c4.z += a[t][2]; c4.w += a[t][3];
            *(float4*)&pls[((w - 4) * TT + t) * 256 + l * 4] = c4;
        }
    }
    __syncthreads();

    if (w < TT) {
        const int t = w;
        float p[4] = {0, 0, 0, 0};
        #pragma unroll
        for (int g = 0; g < 4; ++g) {
            float4 pp = *(const float4*)&pls[(g * TT + t) * 256 + l * 4];
            p[0] += pp.x; p[1] += pp.y; p[2] += pp.z; p[3] += pp.w;
        }
        const int len = lens[b];
        const int s0 = l * 4;
        float sc[4];
        #pragma unroll
        for (int c = 0; c < 4; ++c)
            sc[c] = (s0 + c < len) ? -2.0f * p[c] : -INFINITY;
        float mx = fmaxf(fmaxf(sc[0], sc[1]), fmaxf(sc[2], sc[3]));
        #pragma unroll
        for (int off = 32; off; off >>= 1) mx = fmaxf(mx, __shfl_xor(mx, off));
        float ex[4]; float sum = 0.0f;
        #pragma unroll
        for (int c = 0; c < 4; ++c) { ex[c] = __expf(sc[c] - mx); sum += ex[c]; }
        #pragma unroll
        for (int off = 32; off; off >>= 1) sum += __shfl_xor(sum, off);
        const float inv = RCP(sum);
        *(float4*)&wls[t * SD + s0] = make_float4(ex[0]*inv, ex[1]*inv, ex[2]*inv, ex[3]*inv);
    }
    __syncthreads();

    const int sg = tid >> 7;
    const int h4 = (tid & 127) * 4;
    float* avred = pls;
    float4 o[TT];
    #pragma unroll
    for (int t = 0; t < TT; ++t) o[t] = make_float4(0.f, 0.f, 0.f, 0.f);
    {
        const float* eb = enc + (size_t)b * SD * HD + h4;
        #pragma unroll 2
        for (int ss = 0; ss < 64; ++ss) {
            const int s = sg * 64 + ss;
            float4 evv = *(const float4*)(eb + (size_t)s * HD);
            float wt[TT];
            #pragma unroll
            for (int t = 0; t < TT; ++t) wt[t] = wls[t * SD + s];
            #pragma unroll
            for (int t = 0; t < TT; ++t) {
                o[t].x = fmaf(wt[t], evv.x, o[t].x);
                o[t].y = fmaf(wt[t], evv.y, o[t].y);
                o[t].z = fmaf(wt[t], evv.z, o[t].z);
                o[t].w = fmaf(wt[t], evv.w, o[t].w);
            }
        }
    }
    if (sg < 2) {
        #pragma unroll
        for (int t = 0; t < TT; ++t)
            *(float4*)&avred[(size_t)(sg * TT + t) * 512 + h4] = o[t];
    }
    __syncthreads();
    if (sg >= 2) {
        #pragma unroll
        for (int t = 0; t < TT; ++t) {
            float4 c4 = *(const float4*)&avred[(size_t)((sg - 2) * TT + t) * 512 + h4];
            c4.x += o[t].x; c4.y += o[t].y; c4.z += o[t].z; c4.w += o[t].w;
            *(float4*)&avred[(size_t)((sg - 2) * TT + t) * 512 + h4] = c4;
        }
    }
    __syncthreads();

    if (tid < TT * 128) {
        const int t  = tid >> 7;
        const int hh = (tid & 127) * 4;
        float4 x0 = *(const float4*)&avred[(size_t)(0 * TT + t) * 512 + hh];
        float4 x1 = *(const float4*)&avred[(size_t)(1 * TT + t) * 512 + hh];
        float4 r = make_float4(x0.x + x1.x, x0.y + x1.y, x0.z + x1.z, x0.w + x1.w);
        *(float4*)(out + ((size_t)b * TD + t0 + t) * HD + hh) = r;
    }
}

// ================= PHASE B, 1024-thread TT=8, MLP-batched streams (R6) =================
// Identical structure/summation order to R5's phaseB1024, except the score and AV loops
// load 8 independent rows into registers (static fully-unrolled indices) before compute;
// #pragma unroll 1 on the batch loop pins the pipelined shape. 8 loads in flight/wave.
__device__ __forceinline__ void phaseB1024X(
    int b, int t0, int tid, float* smem,
    const float* __restrict__ enc, const float* __restrict__ encT,
    const float* __restrict__ qryf, const float* __restrict__ v,
    const int* __restrict__ lens, float* __restrict__ out)
{
    const int l = tid & 63;
    const int w = tid >> 6;          // 0..15

    float* qls = smem;               // [t][j] 8*512 floats
    float* pls = smem + 4096;        // [4][8][256] floats; aliased avred
    float* wls = smem + 12288;       // [8][256] floats

    {   // stage E_q: qls[t][j]
        const float* qf = qryf + ((size_t)b * TD + t0) * HD;
        const int j = tid & 511;
        #pragma unroll
        for (int t = (tid >> 9); t < 8; t += 2)
            qls[t * 512 + j] = qf[t * HD + j];
    }
    __syncthreads();

    // ---- scores: wave w covers j in [w*32,(w+1)*32); lane owns s = 4l..4l+3 ----
    float a[8][4];
    #pragma unroll
    for (int t = 0; t < 8; ++t)
        #pragma unroll
        for (int c = 0; c < 4; ++c) a[t][c] = 0.0f;
    {
        const int jbase = w * 32;
        const float* ep = encT + (size_t)b * HD * SD + (size_t)jbase * SD + l * 4;
        #pragma unroll 1
        for (int j0 = 0; j0 < 32; j0 += 8) {
            float4 e8[8];
            #pragma unroll
            for (int u = 0; u < 8; ++u)
                e8[u] = *(const float4*)(ep + (size_t)(j0 + u) * SD);   // 8 in flight
            #pragma unroll
            for (int u = 0; u < 8; ++u) {
                const int jj = j0 + u;
                const float vj = v[jbase + jj];                          // uniform
                float qv[8];
                #pragma unroll
                for (int t = 0; t < 8; ++t) qv[t] = qls[t * 512 + jbase + jj];
                float ev[4] = {e8[u].x, e8[u].y, e8[u].z, e8[u].w};
                #pragma unroll
                for (int t = 0; t < 8; ++t)
                    #pragma unroll
                    for (int c = 0; c < 4; ++c) {
                        float p = fmaf(ev[c], qv[t], 1.0f);
                        a[t][c] = fmaf(vj, RCP(p), a[t][c]);
                    }
            }
        }
    }
    // ---- 4-slot partial combine, 4 stages ----
    if (w < 4) {
        #pragma unroll
        for (int t = 0; t < 8; ++t)
            *(float4*)&pls[(w * 8 + t) * 256 + l * 4] =
                make_float4(a[t][0], a[t][1], a[t][2], a[t][3]);
    }
    __syncthreads();
    if (w >= 4 && w < 8) {
        #pragma unroll
        for (int t = 0; t < 8; ++t) {
            float4 c4 = *(const float4*)&pls[((w - 4) * 8 + t) * 256 + l * 4];
            c4.x += a[t][0]; c4.y += a[t][1]; c4.z += a[t][2]; c4.w += a[t][3];
            *(float4*)&pls[((w - 4) * 8 + t) * 256 + l * 4] = c4;
        }
    }
    __syncthreads();
    if (w >= 8 && w < 12) {
        #pragma unroll
        for (int t = 0; t < 8; ++t) {
            float4 c4 = *(const float4*)&pls[((w - 8) * 8 + t) * 256 + l * 4];
            c4.x += a[t][0]; c4.y += a[t][1]; c4.z += a[t][2]; c4.w += a[t][3];
            *(float4*)&pls[((w - 8) * 8 + t) * 256 + l * 4] = c4;
        }
    }
    __syncthreads();
    if (w >= 12) {
        #pragma unroll
        for (int t = 0; t < 8; ++t) {
            float4 c4 = *(const float4*)&pls[((w - 12) * 8 + t) * 256 + l * 4];
            c4.x += a[t][0]; c4.y += a[t][1]; c4.z += a[t][2]; c4.w += a[t][3];
            *(float4*)&pls[((w - 12) * 8 + t) * 256 + l * 4] = c4;
        }
    }
    __syncthreads();

    // ---- combine 4 slots + masked softmax ----
    if (w < 8) {
        const int t = w;
        float p[4] = {0, 0, 0, 0};
        #pragma unroll
        for (int g = 0; g < 4; ++g) {
            float4 pp = *(const float4*)&pls[(g * 8 + t) * 256 + l * 4];
            p[0] += pp.x; p[1] += pp.y; p[2] += pp.z; p[3] += pp.w;
        }
        const int len = lens[b];
        const int s0 = l * 4;
        float sc[4];
        #pragma unroll
        for (int c = 0; c < 4; ++c)
            sc[c] = (s0 + c < len) ? -2.0f * p[c] : -INFINITY;
        float mx = fmaxf(fmaxf(sc[0], sc[1]), fmaxf(sc[2], sc[3]));
        #pragma unroll
        for (int off = 32; off; off >>= 1) mx = fmaxf(mx, __shfl_xor(mx, off));
        float ex[4]; float sum = 0.0f;
        #pragma unroll
        for (int c = 0; c < 4; ++c) { ex[c] = __expf(sc[c] - mx); sum += ex[c]; }
        #pragma unroll
        for (int off = 32; off; off >>= 1) sum += __shfl_xor(sum, off);
        const float inv = RCP(sum);
        *(float4*)&wls[t * SD + s0] = make_float4(ex[0]*inv, ex[1]*inv, ex[2]*inv, ex[3]*inv);
    }
    __syncthreads();

    // ---- AV: thread owns (h-float4, s-slice sg of 32); batched 8-deep loads ----
    const int sg = tid >> 7;          // 0..7
    const int h4 = (tid & 127) * 4;
    float* avred = pls;               // [2][8][512]
    float4 o[8];
    #pragma unroll
    for (int t = 0; t < 8; ++t) o[t] = make_float4(0.f, 0.f, 0.f, 0.f);
    {
        const float* eb = enc + (size_t)b * SD * HD + h4;
        #pragma unroll 1
        for (int s0b = 0; s0b < 32; s0b += 8) {
            float4 ev8[8];
            #pragma unroll
            for (int u = 0; u < 8; ++u)
                ev8[u] = *(const float4*)(eb + (size_t)(sg * 32 + s0b + u) * HD);
            #pragma unroll
            for (int u = 0; u < 8; ++u) {
                const int s = sg * 32 + s0b + u;
                float wt[8];
                #pragma unroll
                for (int t = 0; t < 8; ++t) wt[t] = wls[t * SD + s];
                #pragma unroll
                for (int t = 0; t < 8; ++t) {
                    o[t].x = fmaf(wt[t], ev8[u].x, o[t].x);
                    o[t].y = fmaf(wt[t], ev8[u].y, o[t].y);
                    o[t].z = fmaf(wt[t], ev8[u].z, o[t].z);
                    o[t].w = fmaf(wt[t], ev8[u].w, o[t].w);
                }
            }
        }
    }
    if (sg < 2) {
        #pragma unroll
        for (int t = 0; t < 8; ++t)
            *(float4*)&avred[(size_t)(sg * 8 + t) * 512 + h4] = o[t];
    }
    __syncthreads();
    if (sg >= 2 && sg < 4) {
        #pragma unroll
        for (int t = 0; t < 8; ++t) {
            float4 c4 = *(const float4*)&avred[(size_t)((sg - 2) * 8 + t) * 512 + h4];
            c4.x += o[t].x; c4.y += o[t].y; c4.z += o[t].z; c4.w += o[t].w;
            *(float4*)&avred[(size_t)((sg - 2) * 8 + t) * 512 + h4] = c4;
        }
    }
    __syncthreads();
    if (sg >= 4 && sg < 6) {
        #pragma unroll
        for (int t = 0; t < 8; ++t) {
            float4 c4 = *(const float4*)&avred[(size_t)((sg - 4) * 8 + t) * 512 + h4];
            c4.x += o[t].x; c4.y += o[t].y; c4.z += o[t].z; c4.w += o[t].w;
            *(float4*)&avred[(size_t)((sg - 4) * 8 + t) * 512 + h4] = c4;
        }
    }
    __syncthreads();
    if (sg >= 6) {
        #pragma unroll
        for (int t = 0; t < 8; ++t) {
            float4 c4 = *(const float4*)&avred[(size_t)((sg - 6) * 8 + t) * 512 + h4];
            c4.x += o[t].x; c4.y += o[t].y; c4.z += o[t].z; c4.w += o[t].w;
            *(float4*)&avred[(size_t)((sg - 6) * 8 + t) * 512 + h4] = c4;
        }
    }
    __syncthreads();

    {
        const int t  = tid >> 7;
        const int hh = (tid & 127) * 4;
        float4 x0 = *(const float4*)&avred[(size_t)(0 * 8 + t) * 512 + hh];
        float4 x1 = *(const float4*)&avred[(size_t)(1 * 8 + t) * 512 + hh];
        float4 r = make_float4(x0.x + x1.x, x0.y + x1.y, x0.z + x1.z, x0.w + x1.w);
        *(float4*)(out + ((size_t)b * TD + t0 + t) * HD + hh) = r;
    }
}

// ================= PHASE B, 1024-thread TT=8 (R5-proven, kept as tier-2) =================
__device__ __forceinline__ void phaseB1024(
    int b, int t0, int tid, float* smem,
    const float* __restrict__ enc, const float* __restrict__ encT,
    const float* __restrict__ qryf, const float* __restrict__ v,
    const int* __restrict__ lens, float* __restrict__ out)
{
    const int l = tid & 63;
    const int w = tid >> 6;

    float* qls = smem;
    float* pls = smem + 4096;
    float* wls = smem + 12288;

    {
        const float* qf = qryf + ((size_t)b * TD + t0) * HD;
        const int j = tid & 511;
        #pragma unroll
        for (int t = (tid >> 9); t < 8; t += 2)
            qls[t * 512 + j] = qf[t * HD + j];
    }
    __syncthreads();

    float a[8][4];
    #pragma unroll
    for (int t = 0; t < 8; ++t)
        #pragma unroll
        for (int c = 0; c < 4; ++c) a[t][c] = 0.0f;
    {
        const int jbase = w * 32;
        const float* ep = encT + (size_t)b * HD * SD + (size_t)jbase * SD + l * 4;
        #pragma unroll 4
        for (int jj = 0; jj < 32; ++jj) {
            float4 e = *(const float4*)(ep + (size_t)jj * SD);
            float vj = v[jbase + jj];
            float qv[8];
            #pragma unroll
            for (int t = 0; t < 8; ++t) qv[t] = qls[t * 512 + jbase + jj];
            float ev[4] = {e.x, e.y, e.z, e.w};
            #pragma unroll
            for (int t = 0; t < 8; ++t)
                #pragma unroll
                for (int c = 0; c < 4; ++c) {
                    float p = fmaf(ev[c], qv[t], 1.0f);
                    a[t][c] = fmaf(vj, RCP(p), a[t][c]);
                }
        }
    }
    if (w < 4) {
        #pragma unroll
        for (int t = 0; t < 8; ++t)
            *(float4*)&pls[(w * 8 + t) * 256 + l * 4] =
                make_float4(a[t][0], a[t][1], a[t][2], a[t][3]);
    }
    __syncthreads();
    if (w >= 4 && w < 8) {
        #pragma unroll
        for (int t = 0; t < 8; ++t) {
            float4 c4 = *(const float4*)&pls[((w - 4) * 8 + t) * 256 + l * 4];
            c4.x += a[t][0]; c4.y += a[t][1]; c4.z += a[t][2]; c4.w += a[t][3];
            *(float4*)&pls[((w - 4) * 8 + t) * 256 + l * 4] = c4;
        }
    }
    __syncthreads();
    if (w >= 8 && w < 12) {
        #pragma unroll
        for (int t = 0; t < 8; ++t) {
            float4 c4 = *(const float4*)&pls[((w - 8) * 8 + t) * 256 + l * 4];
            c4.x += a[t][0]; c4.y += a[t][1]; c4.z += a[t][2]; c4.w += a[t][3];
            *(float4*)&pls[((w - 8) * 8 + t) * 256 + l * 4] = c4;
        }
    }
    __syncthreads();
    if (w >= 12) {
        #pragma unroll
        for (int t = 0; t < 8; ++t) {
            float4 c4 = *(const float4*)&pls[((w - 12) * 8 + t) * 256 + l * 4];
            c4.x += a[t][0]; c4.y += a[t][1]; c4.z += a[t][2]; c4.w += a[t][3];
            *(float4*)&pls[((w - 12) * 8 + t) * 256 + l * 4] = c4;
        }
    }
    __syncthreads();

    if (w < 8) {
        const int t = w;
        float p[4] = {0, 0, 0, 0};
        #pragma unroll
        for (int g = 0; g < 4; ++g) {
            float4 pp = *(const float4*)&pls[(g * 8 + t) * 256 + l * 4];
            p[0] += pp.x; p[1] += pp.y; p[2] += pp.z; p[3] += pp.w;
        }
        const int len = lens[b];
        const int s0 = l * 4;
        float sc[4];
        #pragma unroll
        for (int c = 0; c < 4; ++c)
            sc[c] = (s0 + c < len) ? -2.0f * p[c] : -INFINITY;
        float mx = fmaxf(fmaxf(sc[0], sc[1]), fmaxf(sc[2], sc[3]));
        #pragma unroll
        for (int off = 32; off; off >>= 1) mx = fmaxf(mx, __shfl_xor(mx, off));
        float ex[4]; float sum = 0.0f;
        #pragma unroll
        for (int c = 0; c < 4; ++c) { ex[c] = __expf(sc[c] - mx); sum += ex[c]; }
        #pragma unroll
        for (int off = 32; off; off >>= 1) sum += __shfl_xor(sum, off);
        const float inv = RCP(sum);
        *(float4*)&wls[t * SD + s0] = make_float4(ex[0]*inv, ex[1]*inv, ex[2]*inv, ex[3]*inv);
    }
    __syncthreads();

    const int sg = tid >> 7;
    const int h4 = (tid & 127) * 4;
    float* avred = pls;
    float4 o[8];
    #pragma unroll
    for (int t = 0; t < 8; ++t) o[t] = make_float4(0.f, 0.f, 0.f, 0.f);
    {
        const float* eb = enc + (size_t)b * SD * HD + h4;
        #pragma unroll 2
        for (int ss = 0; ss < 32; ++ss) {
            const int s = sg * 32 + ss;
            float4 evv = *(const float4*)(eb + (size_t)s * HD);
            float wt[8];
            #pragma unroll
            for (int t = 0; t < 8; ++t) wt[t] = wls[t * SD + s];
            #pragma unroll
            for (int t = 0; t < 8; ++t) {
                o[t].x = fmaf(wt[t], evv.x, o[t].x);
                o[t].y = fmaf(wt[t], evv.y, o[t].y);
                o[t].z = fmaf(wt[t], evv.z, o[t].z);
                o[t].w = fmaf(wt[t], evv.w, o[t].w);
            }
        }
    }
    if (sg < 2) {
        #pragma unroll
        for (int t = 0; t < 8; ++t)
            *(float4*)&avred[(size_t)(sg * 8 + t) * 512 + h4] = o[t];
    }
    __syncthreads();
    if (sg >= 2 && sg < 4) {
        #pragma unroll
        for (int t = 0; t < 8; ++t) {
            float4 c4 = *(const float4*)&avred[(size_t)((sg - 2) * 8 + t) * 512 + h4];
            c4.x += o[t].x; c4.y += o[t].y; c4.z += o[t].z; c4.w += o[t].w;
            *(float4*)&avred[(size_t)((sg - 2) * 8 + t) * 512 + h4] = c4;
        }
    }
    __syncthreads();
    if (sg >= 4 && sg < 6) {
        #pragma unroll
        for (int t = 0; t < 8; ++t) {
            float4 c4 = *(const float4*)&avred[(size_t)((sg - 4) * 8 + t) * 512 + h4];
            c4.x += o[t].x; c4.y += o[t].y; c4.z += o[t].z; c4.w += o[t].w;
            *(float4*)&avred[(size_t)((sg - 4) * 8 + t) * 512 + h4] = c4;
        }
    }
    __syncthreads();
    if (sg >= 6) {
        #pragma unroll
        for (int t = 0; t < 8; ++t) {
            float4 c4 = *(const float4*)&avred[(size_t)((sg - 6) * 8 + t) * 512 + h4];
            c4.x += o[t].x; c4.y += o[t].y; c4.z += o[t].z; c4.w += o[t].w;
            *(float4*)&avred[(size_t)((sg - 6) * 8 + t) * 512 + h4] = c4;
        }
    }
    __syncthreads();

    {
        const int t  = tid >> 7;
        const int hh = (tid & 127) * 4;
        float4 x0 = *(const float4*)&avred[(size_t)(0 * 8 + t) * 512 + hh];
        float4 x1 = *(const float4*)&avred[(size_t)(1 * 8 + t) * 512 + hh];
        float4 r = make_float4(x0.x + x1.x, x0.y + x1.y, x0.z + x1.z, x0.w + x1.w);
        *(float4*)(out + ((size_t)b * TD + t0 + t) * HD + hh) = r;
    }
}

// ============ fusedX: fusedW + MLP-batched phase-B streams (R6 candidate) ============
__global__ __launch_bounds__(1024, 4) void fusedX(
    const float* __restrict__ enc, const float* __restrict__ qry,
    const float* __restrict__ Wh,  const float* __restrict__ Ws,
    const float* __restrict__ v,   const int* __restrict__ lens,
    float* __restrict__ encT, float* __restrict__ qryf, float* __restrict__ out)
{
    __shared__ float smem[14336];   // 56 KB
    const int bid = blockIdx.x;     // 0..255
    const int tid = threadIdx.x;

    phaseA1024(bid, tid, smem, enc, qry, Wh, Ws, encT, qryf);
    __syncthreads();
    phaseA1024(bid + 256, tid, smem, enc, qry, Wh, Ws, encT, qryf);

    cg::this_grid().sync();

    phaseB1024X(bid & 7, (bid >> 3) * 8, tid, smem, enc, encT, qryf, v, lens, out);
}

// ============ fusedW: R5-proven (88.8 us), tier-2 ============
__global__ __launch_bounds__(1024, 4) void fusedW(
    const float* __restrict__ enc, const float* __restrict__ qry,
    const float* __restrict__ Wh,  const float* __restrict__ Ws,
    const float* __restrict__ v,   const int* __restrict__ lens,
    float* __restrict__ encT, float* __restrict__ qryf, float* __restrict__ out)
{
    __shared__ float smem[14336];   // 56 KB
    const int bid = blockIdx.x;     // 0..255
    const int tid = threadIdx.x;

    phaseA1024(bid, tid, smem, enc, qry, Wh, Ws, encT, qryf);
    __syncthreads();
    phaseA1024(bid + 256, tid, smem, enc, qry, Wh, Ws, encT, qryf);

    cg::this_grid().sync();

    phaseB1024(bid & 7, (bid >> 3) * 8, tid, smem, enc, encT, qryf, v, lens, out);
}

// ============ fused512: proven r2 config (~102 us), tier-3 ============
__global__ __launch_bounds__(512) void fused512(
    const float* __restrict__ enc, const float* __restrict__ qry,
    const float* __restrict__ Wh,  const float* __restrict__ Ws,
    const float* __restrict__ v,   const int* __restrict__ lens,
    float* __restrict__ encT, float* __restrict__ qryf, float* __restrict__ out)
{
    __shared__ float smem[7168];   // 28 KB
    const int bid = blockIdx.x;
    phaseA(bid, threadIdx.x, smem, enc, qry, Wh, Ws, encT, qryf);
    cg::this_grid().sync();
    phaseB<4>(bid & 7, (bid >> 3) * 4, threadIdx.x, smem,
              enc, encT, qryf, v, lens, out);
}

// ================= fallback pair (proven R8 proj + R7 attn) =================
__global__ __launch_bounds__(256) void proj_fb(
    const float* __restrict__ enc, const float* __restrict__ qry,
    const float* __restrict__ Wh,  const float* __restrict__ Ws,
    float* __restrict__ encT, float* __restrict__ qryf)
{
    __shared__ _Float16 LA[64 * LSTR], LB[64 * LSTR];

    const int tid = threadIdx.x;
    const int l = tid & 63, w = tid >> 6;
    const int rf = l & 15, q = l >> 4;
    const int my = blockIdx.y;
    const bool isq = my >= 32;
    const int m0 = my * 64;
    const int n0 = blockIdx.x * 64;

    const int srow = tid >> 2;
    const int scol = (tid & 3) * 8;
    const float* Abase = isq
        ? qry + (size_t)(m0 - 2048 + srow) * HD + scol
        : enc + (size_t)(m0 + srow) * HD + scol;
    const float* Bbase = (isq ? Ws : Wh) + (size_t)(n0 + srow) * HD + scol;

    const int mi = (w & 1) * 32, ni = (w >> 1) * 32;
    float4v acc[2][2] = {{{0,0,0,0},{0,0,0,0}},{{0,0,0,0},{0,0,0,0}}};

    float4 a0 = *(const float4*)(Abase);
    float4 a1 = *(const float4*)(Abase + 4);
    float4 b0 = *(const float4*)(Bbase);
    float4 b1 = *(const float4*)(Bbase + 4);

    for (int ks = 0; ks < 16; ++ks) {
        if (ks) __syncthreads();
        {
            float af[8] = {a0.x,a0.y,a0.z,a0.w,a1.x,a1.y,a1.z,a1.w};
            float bf[8] = {b0.x,b0.y,b0.z,b0.w,b1.x,b1.y,b1.z,b1.w};
            half8 ha, hb;
            #pragma unroll
            for (int i = 0; i < 8; ++i) { ha[i] = (_Float16)af[i]; hb[i] = (_Float16)bf[i]; }
            *(half8*)&LA[srow * LSTR + scol] = ha;
            *(half8*)&LB[srow * LSTR + scol] = hb;
        }
        __syncthreads();
        if (ks + 1 < 16) {
            const int ko = (ks + 1) * 32;
            a0 = *(const float4*)(Abase + ko);
            a1 = *(const float4*)(Abase + ko + 4);
            b0 = *(const float4*)(Bbase + ko);
            b1 = *(const float4*)(Bbase + ko + 4);
        }
        half8 ah[2], bh[2];
        #pragma unroll
        for (int i = 0; i < 2; ++i) {
            ah[i] = *(const half8*)&LA[(mi + i * 16 + rf) * LSTR + q * 8];
            bh[i] = *(const half8*)&LB[(ni + i * 16 + rf) * LSTR + q * 8];
        }
        #pragma unroll
        for (int i = 0; i < 2; ++i)
            #pragma unroll
            for (int j = 0; j < 2; ++j)
                acc[i][j] = __builtin_amdgcn_mfma_f32_16x16x32_f16(ah[i], bh[j], acc[i][j], 0, 0, 0);
    }

    if (!isq) {
        const int b  = m0 >> 8;
        const int sb = (m0 & 255) + mi + q * 4;
        float* base = encT + (size_t)b * HD * SD;
        #pragma unroll
        for (int i = 0; i < 2; ++i)
            #pragma unroll
            for (int j = 0; j < 2; ++j) {
                float4 o = make_float4(exp2_sat(acc[i][j][0]*K2F), exp2_sat(acc[i][j][1]*K2F),
                                       exp2_sat(acc[i][j][2]*K2F), exp2_sat(acc[i][j][3]*K2F));
                *(float4*)(base + (size_t)(n0 + ni + j * 16 + rf) * SD + sb + i * 16) = o;
            }
    } else {
        const int mrow = (m0 - 2048) + mi + q * 4;
        #pragma unroll
        for (int i = 0; i < 2; ++i)
            #pragma unroll
            for (int j = 0; j < 2; ++j)
                #pragma unroll
                for (int r = 0; r < 4; ++r)
                    qryf[(size_t)(mrow + i * 16 + r) * HD + n0 + ni + j * 16 + rf] =
                        exp2_sat(acc[i][j][r] * K2F);
    }
}

__global__ __launch_bounds__(512) void attn_fb(
    const float* __restrict__ enc, const float* __restrict__ encT,
    const float* __restrict__ qryf, const float* __restrict__ v,
    const int* __restrict__ lens, float* __restrict__ out)
{
    __shared__ float qls[HD * 4];
    __shared__ float pls[8 * 4 * 256];
    __shared__ float wls[4 * SD];

    const int blk = blockIdx.x;
    const int b   = blk >> 6;
    const int t0  = (blk & 63) * 4;
    const int tid = threadIdx.x;
    const int w   = tid >> 6;
    const int l   = tid & 63;

    {
        const float* qf = qryf + ((size_t)b * TD + t0) * HD;
        float4 qv;
        qv.x = qf[0 * HD + tid]; qv.y = qf[1 * HD + tid];
        qv.z = qf[2 * HD + tid]; qv.w = qf[3 * HD + tid];
        *(float4*)&qls[tid * 4] = qv;
    }
    __syncthreads();

    float a[4][4];
    #pragma unroll
    for (int t = 0; t < 4; ++t)
        #pragma unroll
        for (int c = 0; c < 4; ++c) a[t][c] = 0.0f;
    {
        const float* ep = encT + (size_t)b * HD * SD + (size_t)(w * 64) * SD + l * 4;
        const int jbase = w * 64;
        #pragma unroll 4
        for (int jj = 0; jj < 64; ++jj) {
            float4 e = *(const float4*)(ep + (size_t)jj * SD);
            float4 q4 = *(const float4*)&qls[(jbase + jj) * 4];
            float vj = v[jbase + jj];
            float ev[4] = {e.x, e.y, e.z, e.w};
            float qv[4] = {q4.x, q4.y, q4.z, q4.w};
            #pragma unroll
            for (int t = 0; t < 4; ++t)
                #pragma unroll
                for (int c = 0; c < 4; ++c) {
                    float p = fmaf(ev[c], qv[t], 1.0f);
                    a[t][c] = fmaf(vj, RCP(p), a[t][c]);
                }
        }
    }
    #pragma unroll
    for (int t = 0; t < 4; ++t)
        *(float4*)&pls[(w * 4 + t) * 256 + l * 4] = make_float4(a[t][0], a[t][1], a[t][2], a[t][3]);
    __syncthreads();

    if (w < 4) {
        const int t = w;
        float p[4] = {0, 0, 0, 0};
        #pragma unroll
        for (int g = 0; g < 8; ++g) {
            float4 pp = *(const float4*)&pls[(g * 4 + t) * 256 + l * 4];
            p[0] += pp.x; p[1] += pp.y; p[2] += pp.z; p[3] += pp.w;
        }
        const int len = lens[b];
        const int s0 = l * 4;
        float sc[4];
        #pragma unroll
        for (int c = 0; c < 4; ++c)
            sc[c] = (s0 + c < len) ? -2.0f * p[c] : -INFINITY;
        float mx = fmaxf(fmaxf(sc[0], sc[1]), fmaxf(sc[2], sc[3]));
        #pragma unroll
        for (int off = 32; off; off >>= 1) mx = fmaxf(mx, __shfl_xor(mx, off));
        float ex[4]; float sum = 0.0f;
        #pragma unroll
        for (int c = 0; c < 4; ++c) { ex[c] = __expf(sc[c] - mx); sum += ex[c]; }
        #pragma unroll
        for (int off = 32; off; off >>= 1) sum += __shfl_xor(sum, off);
        const float inv = RCP(sum);
        *(float4*)&wls[t * SD + s0] = make_float4(ex[0]*inv, ex[1]*inv, ex[2]*inv, ex[3]*inv);
    }
    __syncthreads();

    const int g  = tid >> 7;
    const int h4 = (tid & 127) * 4;
    float* avred = pls;
    {
        const float* eb = enc + (size_t)b * SD * HD + h4;
        float4 o[4] = {{0,0,0,0},{0,0,0,0},{0,0,0,0},{0,0,0,0}};
        #pragma unroll 2
        for (int ss = 0; ss < 64; ++ss) {
            const int s = g * 64 + ss;
            float4 evv = *(const float4*)(eb + (size_t)s * HD);
            float wt[4];
            #pragma unroll
            for (int t = 0; t < 4; ++t) wt[t] = wls[t * SD + s];
            #pragma unroll
            for (int t = 0; t < 4; ++t) {
                o[t].x = fmaf(wt[t], evv.x, o[t].x);
                o[t].y = fmaf(wt[t], evv.y, o[t].y);
                o[t].z = fmaf(wt[t], evv.z, o[t].z);
                o[t].w = fmaf(wt[t], evv.w, o[t].w);
            }
        }
        #pragma unroll
        for (int t = 0; t < 4; ++t)
            *(float4*)&avred[(size_t)(g * 4 + t) * 512 + h4] = o[t];
    }
    __syncthreads();
    {
        const int t  = tid >> 7;
        const int hh = (tid & 127) * 4;
        float4 r = {0, 0, 0, 0};
        #pragma unroll
        for (int gg = 0; gg < 4; ++gg) {
            float4 x = *(const float4*)&avred[(size_t)(gg * 4 + t) * 512 + hh];
            r.x += x.x; r.y += x.y; r.z += x.z; r.w += x.w;
        }
        *(float4*)(out + ((size_t)b * TD + t0 + t) * HD + hh) = r;
    }
}

extern "C" void kernel_launch(void* const* d_in, const int* in_sizes, int n_in,
                              void* d_out, int out_size, void* d_ws, size_t ws_size,
                              hipStream_t stream) {
    const float* query = (const float*)d_in[0];
    const float* enc   = (const float*)d_in[1];
    const int*   lens  = (const int*)d_in[2];
    const float* W_h   = (const float*)d_in[3];
    const float* W_s   = (const float*)d_in[4];
    const float* v     = (const float*)d_in[5];
    float* out = (float*)d_out;

    char* ws = (char*)d_ws;
    float* encT = (float*)(ws);                       // 4 MB (B,H,S)  E_e
    float* qryf = (float*)(ws + ((size_t)4 << 20));   // 4 MB (B,T,H)  E_q

    void* args[] = {
        (void*)&enc, (void*)&query, (void*)&W_h, (void*)&W_s,
        (void*)&v, (void*)&lens, (void*)&encT, (void*)&qryf, (void*)&out
    };

    // Tier 1: fusedX (MLP-batched streams). Host-side occupancy pre-screen.
    int nb = 0;
    hipError_t oerr = hipOccupancyMaxActiveBlocksPerMultiprocessor(
        &nb, (const void*)fusedX, 1024, 0);
    if (oerr == hipSuccess && nb >= 1) {
        hipError_t lerr = hipLaunchCooperativeKernel((const void*)fusedX,
                                                     dim3(256), dim3(1024), args, 0, stream);
        if (lerr == hipSuccess) return;
    }

    // Tier 2: fusedW (R5-proven, ~89 us).
    nb = 0;
    oerr = hipOccupancyMaxActiveBlocksPerMultiprocessor(
        &nb, (const void*)fusedW, 1024, 0);
    if (oerr == hipSuccess && nb >= 1) {
        hipError_t lerr = hipLaunchCooperativeKernel((const void*)fusedW,
                                                     dim3(256), dim3(1024), args, 0, stream);
        if (lerr == hipSuccess) return;
    }

    // Tier 3: fused512 (r2 config, ~102 us).
    nb = 0;
    oerr = hipOccupancyMaxActiveBlocksPerMultiprocessor(
        &nb, (const void*)fused512, 512, 0);
    if (oerr == hipSuccess && nb >= 2) {
        hipError_t lerr = hipLaunchCooperativeKernel((const void*)fused512,
                                                     dim3(512), dim3(512), args, 0, stream);
        if (lerr == hipSuccess) return;
    }

    // Tier 4: proven two-kernel path.
    dim3 pgrid(HD / 64, 64);
    proj_fb<<<pgrid, 256, 0, stream>>>(enc, query, W_h, W_s, encT, qryf);
    attn_fb<<<BD * (TD / 4), 512, 0, stream>>>(enc, encT, qryf, v, lens, out);
}

// Round 7
// 119.133 us; speedup vs baseline: 1.0223x; 1.0153x over previous
//
#include <hip/hip_runtime.h>
#include <cstddef>
#include <math.h>

#define BD 8
#define TD 256
#define SD 256
#define HD 512
#define K2F 2.885390081777927f    // 2*log2(e): arg of exp2 for e^(2x)

#define EXP2(x) __builtin_amdgcn_exp2f(x)
#define RCP(x)  __builtin_amdgcn_rcpf(x)

typedef __attribute__((ext_vector_type(8))) _Float16 half8;
typedef __attribute__((ext_vector_type(4))) _Float16 half4;
typedef __attribute__((ext_vector_type(4))) float float4v;

// exp2 with arg clamped so E in [2^-80, 2^80]: products overflow to inf -> rcp -> 0,
// underflow to 0 -> r = 1; no inf*0 NaN path possible.
__device__ __forceinline__ float exp2_sat(float x) {
    return EXP2(fminf(fmaxf(x, -80.0f), 80.0f));
}

#define LSTR 40   // LDS row stride (halves) for proj staging

// ================= projK: proj (fp16 MFMA, fused convert), 1024 threads =================
// R4/R5-verified phaseA1024 body (absmax identical across fusedT/fusedW runs).
// One 64x64 tile per block; bid->tile map: x=bid&7 (XCD/batch pin), k=bid>>3.
// Threads 0-511 stage the A tile, 512-1023 stage the B tile; 1 MFMA/wave/k-step.
// NOTE: plain kernel launch — graph-capture-safe (hipLaunchCooperativeKernel is NOT:
// it fails under stream capture, which silently forced the slow fallback in R0-R6).
__global__ __launch_bounds__(1024) void projK(
    const float* __restrict__ enc, const float* __restrict__ qry,
    const float* __restrict__ Wh,  const float* __restrict__ Ws,
    float* __restrict__ encT, float* __restrict__ qryf)
{
    __shared__ float smem[2560];               // 10 KB: LA | LB

    const int bid = blockIdx.x;                // 0..511
    const int tid = threadIdx.x;               // 0..1023
    const int l  = tid & 63;
    const int w  = tid >> 6;                   // wave 0..15
    const int rf = l & 15;
    const int q  = l >> 4;

    _Float16* LA = (_Float16*)smem;            // 64*40 halves = 5120 B
    _Float16* LB = (_Float16*)(smem + 1280);   // +5120 B

    const int x  = bid & 7;                    // XCD / owning batch
    const int k  = bid >> 3;                   // 0..63
    const bool isq = k >= 32;
    const int kk = k & 31;                     // 0..31
    const int my = (isq ? 32 : 0) + x * 4 + (kk & 3);
    const int n0 = (kk >> 2) * 64;
    const int m0 = my * 64;                    // stacked row 0..4095

    const bool stagesA = (tid < 512);          // wave-uniform (waves 0-7 vs 8-15)
    const int srow = (tid >> 3) & 63;          // staging row 0..63
    const int scol = (tid & 7) * 4;            // staging col (floats)
    const float* Sbase = stagesA
        ? (isq ? qry + (size_t)(m0 - 2048 + srow) * HD
               : enc + (size_t)(m0 + srow) * HD) + scol
        : (isq ? Ws : Wh) + (size_t)(n0 + srow) * HD + scol;
    _Float16* Ldst = (stagesA ? LA : LB) + srow * LSTR + scol;

    const int mi = (w & 3) * 16;               // wave row-strip (4)
    const int ni = (w >> 2) * 16;              // wave col-strip (4)

    float4v acc = {0, 0, 0, 0};

    float4 a0 = *(const float4*)(Sbase);

    for (int ks = 0; ks < 16; ++ks) {
        if (ks) __syncthreads();
        {
            half4 ha;
            ha[0]=(_Float16)a0.x; ha[1]=(_Float16)a0.y; ha[2]=(_Float16)a0.z; ha[3]=(_Float16)a0.w;
            *(half4*)Ldst = ha;
        }
        __syncthreads();
        if (ks + 1 < 16) a0 = *(const float4*)(Sbase + (ks + 1) * 32);
        half8 ah = *(const half8*)&LA[(mi + rf) * LSTR + q * 8];
        half8 bh = *(const half8*)&LB[(ni + rf) * LSTR + q * 8];
        acc = __builtin_amdgcn_mfma_f32_16x16x32_f16(ah, bh, acc, 0, 0, 0);
    }

    // Epilogue (verified map: m-local = mi + q*4 + r, n-local = ni + rf).
    if (!isq) {
        const int b  = m0 >> 8;                // == x by construction
        const int sb = (m0 & 255) + mi + q * 4;
        float* base = encT + (size_t)b * HD * SD;
        float4 o = make_float4(exp2_sat(acc[0]*K2F), exp2_sat(acc[1]*K2F),
                               exp2_sat(acc[2]*K2F), exp2_sat(acc[3]*K2F));
        *(float4*)(base + (size_t)(n0 + ni + rf) * SD + sb) = o;
    } else {
        const int mrow = (m0 - 2048) + mi + q * 4;
        #pragma unroll
        for (int r = 0; r < 4; ++r)
            qryf[(size_t)(mrow + r) * HD + n0 + ni + rf] = exp2_sat(acc[r] * K2F);
    }
}

// ================= attnK: attn, TT=8, 1024 threads (R5-proven phaseB1024) =================
// smem: qls [8][512] 16 KB | pls [4][8][256] 32 KB (aliased avred [2][8][512]) | wls [8][256] 8 KB
// Grid 256: b = bid & 7 (XCD pin, matches projK's writes), t0 = (bid>>3)*8.
__global__ __launch_bounds__(1024) void attnK(
    const float* __restrict__ enc, const float* __restrict__ encT,
    const float* __restrict__ qryf, const float* __restrict__ v,
    const int* __restrict__ lens, float* __restrict__ out)
{
    __shared__ float smem[14336];    // 56 KB

    const int bid = blockIdx.x;      // 0..255
    const int tid = threadIdx.x;
    const int b   = bid & 7;
    const int t0  = (bid >> 3) * 8;
    const int l = tid & 63;
    const int w = tid >> 6;          // 0..15

    float* qls = smem;               // [t][j] 8*512 floats
    float* pls = smem + 4096;        // [4][8][256] floats; aliased avred
    float* wls = smem + 12288;       // [8][256] floats

    {   // stage E_q: qls[t][j] (conflict-free writes, broadcast reads)
        const float* qf = qryf + ((size_t)b * TD + t0) * HD;
        const int j = tid & 511;
        #pragma unroll
        for (int t = (tid >> 9); t < 8; t += 2)
            qls[t * 512 + j] = qf[t * HD + j];
    }
    __syncthreads();

    // ---- scores: wave w covers j in [w*32, (w+1)*32); lane owns s = 4l..4l+3 ----
    float a[8][4];
    #pragma unroll
    for (int t = 0; t < 8; ++t)
        #pragma unroll
        for (int c = 0; c < 4; ++c) a[t][c] = 0.0f;
    {
        const int jbase = w * 32;
        const float* ep = encT + (size_t)b * HD * SD + (size_t)jbase * SD + l * 4;
        #pragma unroll 4
        for (int jj = 0; jj < 32; ++jj) {
            float4 e = *(const float4*)(ep + (size_t)jj * SD);  // coalesced 1 KB/wave
            float vj = v[jbase + jj];                           // uniform -> s_load
            float qv[8];
            #pragma unroll
            for (int t = 0; t < 8; ++t) qv[t] = qls[t * 512 + jbase + jj];  // broadcast
            float ev[4] = {e.x, e.y, e.z, e.w};
            #pragma unroll
            for (int t = 0; t < 8; ++t)
                #pragma unroll
                for (int c = 0; c < 4; ++c) {
                    float p = fmaf(ev[c], qv[t], 1.0f);
                    a[t][c] = fmaf(vj, RCP(p), a[t][c]);
                }
        }
    }
    // ---- 4-slot partial combine, 4 stages (slot g accumulates waves g, g+4, g+8, g+12) ----
    if (w < 4) {
        #pragma unroll
        for (int t = 0; t < 8; ++t)
            *(float4*)&pls[(w * 8 + t) * 256 + l * 4] =
                make_float4(a[t][0], a[t][1], a[t][2], a[t][3]);
    }
    __syncthreads();
    if (w >= 4 && w < 8) {
        #pragma unroll
        for (int t = 0; t < 8; ++t) {
            float4 c4 = *(const float4*)&pls[((w - 4) * 8 + t) * 256 + l * 4];
            c4.x += a[t][0]; c4.y += a[t][1]; c4.z += a[t][2]; c4.w += a[t][3];
            *(float4*)&pls[((w - 4) * 8 + t) * 256 + l * 4] = c4;
        }
    }
    __syncthreads();
    if (w >= 8 && w < 12) {
        #pragma unroll
        for (int t = 0; t < 8; ++t) {
            float4 c4 = *(const float4*)&pls[((w - 8) * 8 + t) * 256 + l * 4];
            c4.x += a[t][0]; c4.y += a[t][1]; c4.z += a[t][2]; c4.w += a[t][3];
            *(float4*)&pls[((w - 8) * 8 + t) * 256 + l * 4] = c4;
        }
    }
    __syncthreads();
    if (w >= 12) {
        #pragma unroll
        for (int t = 0; t < 8; ++t) {
            float4 c4 = *(const float4*)&pls[((w - 12) * 8 + t) * 256 + l * 4];
            c4.x += a[t][0]; c4.y += a[t][1]; c4.z += a[t][2]; c4.w += a[t][3];
            *(float4*)&pls[((w - 12) * 8 + t) * 256 + l * 4] = c4;
        }
    }
    __syncthreads();

    // ---- combine 4 slots + masked softmax: wave w<8 handles t=w; lane owns 4 s ----
    if (w < 8) {
        const int t = w;
        float p[4] = {0, 0, 0, 0};
        #pragma unroll
        for (int g = 0; g < 4; ++g) {
            float4 pp = *(const float4*)&pls[(g * 8 + t) * 256 + l * 4];
            p[0] += pp.x; p[1] += pp.y; p[2] += pp.z; p[3] += pp.w;
        }
        const int len = lens[b];
        const int s0 = l * 4;
        float sc[4];
        #pragma unroll
        for (int c = 0; c < 4; ++c)
            sc[c] = (s0 + c < len) ? -2.0f * p[c] : -INFINITY;
        float mx = fmaxf(fmaxf(sc[0], sc[1]), fmaxf(sc[2], sc[3]));
        #pragma unroll
        for (int off = 32; off; off >>= 1) mx = fmaxf(mx, __shfl_xor(mx, off));
        float ex[4]; float sum = 0.0f;
        #pragma unroll
        for (int c = 0; c < 4; ++c) { ex[c] = __expf(sc[c] - mx); sum += ex[c]; }
        #pragma unroll
        for (int off = 32; off; off >>= 1) sum += __shfl_xor(sum, off);
        const float inv = RCP(sum);
        *(float4*)&wls[t * SD + s0] = make_float4(ex[0]*inv, ex[1]*inv, ex[2]*inv, ex[3]*inv);
    }
    __syncthreads();

    // ---- AV: thread owns (h-float4, s-slice sg of 32); accumulates all 8 t ----
    const int sg = tid >> 7;          // 0..7 (wave-pair-uniform)
    const int h4 = (tid & 127) * 4;
    float* avred = pls;               // [2][8][512] = 8192 floats
    float4 o[8];
    #pragma unroll
    for (int t = 0; t < 8; ++t) o[t] = make_float4(0.f, 0.f, 0.f, 0.f);
    {
        const float* eb = enc + (size_t)b * SD * HD + h4;
        #pragma unroll 2
        for (int ss = 0; ss < 32; ++ss) {
            const int s = sg * 32 + ss;
            float4 evv = *(const float4*)(eb + (size_t)s * HD);
            float wt[8];
            #pragma unroll
            for (int t = 0; t < 8; ++t) wt[t] = wls[t * SD + s];  // broadcast
            #pragma unroll
            for (int t = 0; t < 8; ++t) {
                o[t].x = fmaf(wt[t], evv.x, o[t].x);
                o[t].y = fmaf(wt[t], evv.y, o[t].y);
                o[t].z = fmaf(wt[t], evv.z, o[t].z);
                o[t].w = fmaf(wt[t], evv.w, o[t].w);
            }
        }
    }
    // 2-slot reduce in 4 stages (slot g accumulates sg = g, g+2, g+4, g+6)
    if (sg < 2) {
        #pragma unroll
        for (int t = 0; t < 8; ++t)
            *(float4*)&avred[(size_t)(sg * 8 + t) * 512 + h4] = o[t];
    }
    __syncthreads();
    if (sg >= 2 && sg < 4) {
        #pragma unroll
        for (int t = 0; t < 8; ++t) {
            float4 c4 = *(const float4*)&avred[(size_t)((sg - 2) * 8 + t) * 512 + h4];
            c4.x += o[t].x; c4.y += o[t].y; c4.z += o[t].z; c4.w += o[t].w;
            *(float4*)&avred[(size_t)((sg - 2) * 8 + t) * 512 + h4] = c4;
        }
    }
    __syncthreads();
    if (sg >= 4 && sg < 6) {
        #pragma unroll
        for (int t = 0; t < 8; ++t) {
            float4 c4 = *(const float4*)&avred[(size_t)((sg - 4) * 8 + t) * 512 + h4];
            c4.x += o[t].x; c4.y += o[t].y; c4.z += o[t].z; c4.w += o[t].w;
            *(float4*)&avred[(size_t)((sg - 4) * 8 + t) * 512 + h4] = c4;
        }
    }
    __syncthreads();
    if (sg >= 6) {
        #pragma unroll
        for (int t = 0; t < 8; ++t) {
            float4 c4 = *(const float4*)&avred[(size_t)((sg - 6) * 8 + t) * 512 + h4];
            c4.x += o[t].x; c4.y += o[t].y; c4.z += o[t].z; c4.w += o[t].w;
            *(float4*)&avred[(size_t)((sg - 6) * 8 + t) * 512 + h4] = c4;
        }
    }
    __syncthreads();

    // final reduce + store: thread owns (t = tid>>7 in 0..7, h-float4)
    {
        const int t  = tid >> 7;
        const int hh = (tid & 127) * 4;
        float4 x0 = *(const float4*)&avred[(size_t)(0 * 8 + t) * 512 + hh];
        float4 x1 = *(const float4*)&avred[(size_t)(1 * 8 + t) * 512 + hh];
        float4 r = make_float4(x0.x + x1.x, x0.y + x1.y, x0.z + x1.z, x0.w + x1.w);
        *(float4*)(out + ((size_t)b * TD + t0 + t) * HD + hh) = r;
    }
}

extern "C" void kernel_launch(void* const* d_in, const int* in_sizes, int n_in,
                              void* d_out, int out_size, void* d_ws, size_t ws_size,
                              hipStream_t stream) {
    const float* query = (const float*)d_in[0];
    const float* enc   = (const float*)d_in[1];
    const int*   lens  = (const int*)d_in[2];
    const float* W_h   = (const float*)d_in[3];
    const float* W_s   = (const float*)d_in[4];
    const float* v     = (const float*)d_in[5];
    float* out = (float*)d_out;

    char* ws = (char*)d_ws;
    float* encT = (float*)(ws);                       // 4 MB (B,H,S)  E_e
    float* qryf = (float*)(ws + ((size_t)4 << 20));   // 4 MB (B,T,H)  E_q

    // Plain launches only — graph-capture-safe. The kernel boundary provides the
    // device-wide sync that grid.sync() gave the cooperative version (R5: 89 us).
    projK<<<dim3(512), dim3(1024), 0, stream>>>(enc, query, W_h, W_s, encT, qryf);
    attnK<<<dim3(256), dim3(1024), 0, stream>>>(enc, encT, qryf, v, lens, out);
}